// Round 7
// baseline (426.263 us; speedup 1.0000x reference)
//
#include <hip/hip_runtime.h>

typedef float f32x4 __attribute__((ext_vector_type(4)));
typedef short s16x8 __attribute__((ext_vector_type(8)));
typedef unsigned short ush4 __attribute__((ext_vector_type(4)));

#define B_ 32
#define C_ 256
#define H_ 56
#define W_ 56
#define HW_ (H_*W_)     // 3136
#define CH_ 14336       // C_*H_ == C_*W_
#define NHT 28          // H_/2 row-tiles per batch
#define CPH 68          // ushort stride scout/swout (8B-aligned b64 frag loads)
#define SGP 57          // ushort stride for e-tiles

// LDS layout (73248 B total -> 2 blocks/CU). sg1 aliases scout, sred aliases
// swout: both targets are written only after the last MFMA read (bar2).
#define OFF_SG0   0          // 29184 B (256*57*2)
#define OFF_SCOUT 29184      // 34816 B (256*68*2)  [∪ sg1 29184]
#define OFF_SWOUT 64000      //  8704 B (64*68*2)   [∪ sredB0+sredB1 8192]
#define OFF_SRED0 64000
#define OFF_SRED1 68096
#define OFF_SHOUT 72704      //   544 B (2*68*4)
#define SMEM_SZ   73248

// ---------- helpers ----------
__device__ __forceinline__ unsigned short f2bf(float f) {
    unsigned u = __float_as_uint(f);
    u += 0x7fffu + ((u >> 16) & 1u);     // round-to-nearest-even
    return (unsigned short)(u >> 16);
}
__device__ __forceinline__ float bf2f(unsigned short u) {
    return __uint_as_float((unsigned)u << 16);
}
__device__ __forceinline__ f32x4 bf2f4(ush4 u) {
    f32x4 r; r[0] = bf2f(u[0]); r[1] = bf2f(u[1]); r[2] = bf2f(u[2]); r[3] = bf2f(u[3]);
    return r;
}
__device__ __forceinline__ s16x8 pack8(f32x4 a, f32x4 b) {
    s16x8 r;
    r[0] = (short)f2bf(a[0]); r[1] = (short)f2bf(a[1]);
    r[2] = (short)f2bf(a[2]); r[3] = (short)f2bf(a[3]);
    r[4] = (short)f2bf(b[0]); r[5] = (short)f2bf(b[1]);
    r[6] = (short)f2bf(b[2]); r[7] = (short)f2bf(b[3]);
    return r;
}
__device__ __forceinline__ s16x8 cat8(ush4 a, ush4 b) {
    s16x8 r;
    r[0] = (short)a[0]; r[1] = (short)a[1]; r[2] = (short)a[2]; r[3] = (short)a[3];
    r[4] = (short)b[0]; r[5] = (short)b[1]; r[6] = (short)b[2]; r[7] = (short)b[3];
    return r;
}

// ---------- K1: GAP reductions ----------
__global__ __launch_bounds__(256) void k_reduce(const float* __restrict__ x,
                                                float* __restrict__ gapc,
                                                float* __restrict__ gw,
                                                float* __restrict__ gh) {
    const int b = blockIdx.x >> 8;
    const int c = blockIdx.x & 255;
    const float* px = x + (size_t)(b * C_ + c) * HW_;
    __shared__ float sp[HW_];
    __shared__ float spart[4];
    const int tid = threadIdx.x;
    float tot = 0.f;
    for (int j = tid; j < HW_ / 4; j += 256) {
        f32x4 v = *(const f32x4*)(px + j * 4);
        *(f32x4*)&sp[j * 4] = v;
        tot += v[0] + v[1] + v[2] + v[3];
    }
    for (int d = 32; d > 0; d >>= 1) tot += __shfl_xor(tot, d, 64);
    const int lane = tid & 63, wid = tid >> 6;
    if (lane == 0) spart[wid] = tot;
    __syncthreads();
    if (tid == 0)
        gapc[b * C_ + c] = (spart[0] + spart[1] + spart[2] + spart[3]) * (1.f / HW_);
    if (tid < W_) {
        float s = 0.f;
        for (int h = 0; h < H_; ++h) s += sp[h * W_ + tid];
        atomicAdd(&gw[b * W_ + tid], s);
    } else if (tid >= 64 && tid < 64 + H_) {
        const int h = tid - 64;
        float s = 0.f;
        for (int w = 0; w < W_; ++w) s += sp[h * W_ + w];
        atomicAdd(&gh[b * H_ + h], s);
    }
}

// ---------- K3: fused CP-reconstruct + softmax + conv3d gate ----------
// Both h-rows per pass: MFMA row0 -> e0=exp -> sg0; MFMA row1 -> bar -> e1 ->
// sg1 (aliases scout); one cross-wave SUM (no max: logits ~1e-6, exp safe);
// dual-row 8-channel-chunk conv (load each x row once for 2 rows x 3 ch-taps).
// 4 barriers total. XCD-swizzled block ids: each XCD owns 4 consecutive b's.
__global__ __launch_bounds__(1024)
__attribute__((amdgpu_waves_per_eu(8)))
void k_main(
    const float* __restrict__ x,
    const float* __restrict__ Wc, const float* __restrict__ acp,
    const float* __restrict__ Ww, const float* __restrict__ awp,
    const float* __restrict__ Wh, const float* __restrict__ ahp,
    const float* __restrict__ W3,
    const float* __restrict__ gapc, const float* __restrict__ gw,
    const float* __restrict__ gh,
    float* __restrict__ out)
{
    __shared__ __align__(16) char smem[SMEM_SZ];
    unsigned short* sg0   = (unsigned short*)(smem + OFF_SG0);
    unsigned short* scout = (unsigned short*)(smem + OFF_SCOUT);
    unsigned short* sg1   = scout;                          // alias, post-bar2
    unsigned short* swout = (unsigned short*)(smem + OFF_SWOUT);
    float* sredB0 = (float*)(smem + OFF_SRED0);             // alias swout
    float* sredB1 = (float*)(smem + OFF_SRED1);
    float* shout  = (float*)(smem + OFF_SHOUT);

    // swizzled decode: blocks round-robin XCDs; give each XCD 4 whole batches
    const int bid  = blockIdx.x;
    const int slot = bid >> 3;
    const int b    = (bid & 7) * 4 + slot / NHT;
    const int h0   = (slot % NHT) * 2;

    const int tid  = threadIdx.x;
    const int lane = tid & 63;
    const int wid  = tid >> 6;
    const int g    = lane >> 4;
    const int col  = lane & 15;
    const int lw   = (lane < W_) ? lane : (W_ - 1);
    const float ac = acp[0], aw = awp[0], ah = ahp[0];

    // ----- staging: factor matrices from the GAP results (bf16) -----
    const float* gc = gapc + b * C_;
    for (int idx = tid; idx < C_ * 64; idx += 1024) {
        const int c = idx >> 6, r = idx & 63;
        const float gm = (c >= 1)      ? gc[c - 1] : 0.f;
        const float g0 = gc[c];
        const float gp = (c < C_ - 1)  ? gc[c + 1] : 0.f;
        float v = Wc[r * 3 + 0] * gm + Wc[r * 3 + 1] * g0 + Wc[r * 3 + 2] * gp;
        scout[c * CPH + r] = f2bf((v >= 0.f) ? v : ac * v);
    }
    const float* gwb = gw + b * W_;
    for (int idx = tid; idx < 64 * 64; idx += 1024) {
        const int w = idx >> 6, r = idx & 63;
        float v = 0.f;
        if (w < W_) {
            const float gm = (w >= 1)     ? gwb[w - 1] * (1.f / CH_) : 0.f;
            const float g0 = gwb[w] * (1.f / CH_);
            const float gp = (w < W_ - 1) ? gwb[w + 1] * (1.f / CH_) : 0.f;
            v = Ww[r * 3 + 0] * gm + Ww[r * 3 + 1] * g0 + Ww[r * 3 + 2] * gp;
            v = (v >= 0.f) ? v : aw * v;
        }
        swout[w * CPH + r] = f2bf(v);
    }
    const float* ghb = gh + b * H_;
    if (tid < 2 * 64) {
        const int hr = tid >> 6, r = tid & 63;
        const int h = h0 + hr;
        const float gm = (h >= 1)     ? ghb[h - 1] * (1.f / CH_) : 0.f;
        const float g0 = ghb[h] * (1.f / CH_);
        const float gp = (h < H_ - 1) ? ghb[h + 1] * (1.f / CH_) : 0.f;
        float v = Wh[r * 3 + 0] * gm + Wh[r * 3 + 1] * g0 + Wh[r * 3 + 2] * gp;
        shout[hr * CPH + r] = (v >= 0.f) ? v : ah * v;
    }
    __syncthreads();                                        // bar1

    const int cbase = wid * 16;
    const int crow  = cbase + col;

    // ----- MFMA row0 -----
    f32x4 acc[4];
    #pragma unroll
    for (int t = 0; t < 4; ++t) acc[t] = (f32x4){0,0,0,0};
    #pragma unroll
    for (int kc = 0; kc < 2; ++kc) {
        const int r0 = kc * 32 + g * 4;
        f32x4 ca = bf2f4(*(ush4*)&scout[crow * CPH + r0]);
        f32x4 cb = bf2f4(*(ush4*)&scout[crow * CPH + r0 + 16]);
        f32x4 ha = *(f32x4*)&shout[0 * CPH + r0];
        f32x4 hb = *(f32x4*)&shout[0 * CPH + r0 + 16];
        s16x8 afrag = pack8(ca * ha, cb * hb);
        #pragma unroll
        for (int t = 0; t < 4; ++t)
            acc[t] = __builtin_amdgcn_mfma_f32_16x16x32_bf16(afrag,
                     cat8(*(ush4*)&swout[(t*16+col)*CPH + r0], *(ush4*)&swout[(t*16+col)*CPH + r0 + 16]),
                     acc[t], 0, 0, 0);
    }
    // write e0 = exp(logit) to sg0 (dedicated buffer; readers wait at bar3)
    {
        const int cr = cbase + g * 4;
        #pragma unroll
        for (int t = 0; t < 4; ++t) {
            const int w = t * 16 + col;
            if (w < W_) {
                sg0[(cr + 0) * SGP + w] = f2bf(__expf(acc[t][0]));
                sg0[(cr + 1) * SGP + w] = f2bf(__expf(acc[t][1]));
                sg0[(cr + 2) * SGP + w] = f2bf(__expf(acc[t][2]));
                sg0[(cr + 3) * SGP + w] = f2bf(__expf(acc[t][3]));
            }
        }
    }
    // ----- MFMA row1 -----
    #pragma unroll
    for (int t = 0; t < 4; ++t) acc[t] = (f32x4){0,0,0,0};
    #pragma unroll
    for (int kc = 0; kc < 2; ++kc) {
        const int r0 = kc * 32 + g * 4;
        f32x4 ca = bf2f4(*(ush4*)&scout[crow * CPH + r0]);
        f32x4 cb = bf2f4(*(ush4*)&scout[crow * CPH + r0 + 16]);
        f32x4 ha = *(f32x4*)&shout[1 * CPH + r0];
        f32x4 hb = *(f32x4*)&shout[1 * CPH + r0 + 16];
        s16x8 afrag = pack8(ca * ha, cb * hb);
        #pragma unroll
        for (int t = 0; t < 4; ++t)
            acc[t] = __builtin_amdgcn_mfma_f32_16x16x32_bf16(afrag,
                     cat8(*(ush4*)&swout[(t*16+col)*CPH + r0], *(ush4*)&swout[(t*16+col)*CPH + r0 + 16]),
                     acc[t], 0, 0, 0);
    }
    __syncthreads();                                        // bar2: scout/swout reads done
    {
        const int cr = cbase + g * 4;
        #pragma unroll
        for (int t = 0; t < 4; ++t) {
            const int w = t * 16 + col;
            if (w < W_) {
                sg1[(cr + 0) * SGP + w] = f2bf(__expf(acc[t][0]));
                sg1[(cr + 1) * SGP + w] = f2bf(__expf(acc[t][1]));
                sg1[(cr + 2) * SGP + w] = f2bf(__expf(acc[t][2]));
                sg1[(cr + 3) * SGP + w] = f2bf(__expf(acc[t][3]));
            }
        }
    }
    __syncthreads();                                        // bar3: e-tiles complete

    // ----- softmax denominators (pure sum; logits ~1e-6 so no max needed) -----
    float invS0, invS1;
    {
        float S0 = 0.f, S1 = 0.f;
        #pragma unroll
        for (int k = 0; k < 16; ++k) {
            S0 += bf2f(sg0[(cbase + k) * SGP + lw]);
            S1 += bf2f(sg1[(cbase + k) * SGP + lw]);
        }
        sredB0[wid * 64 + lane] = S0;
        sredB1[wid * 64 + lane] = S1;
        __syncthreads();                                    // bar4
        float T0 = 0.f, T1 = 0.f;
        #pragma unroll
        for (int t = 0; t < 16; ++t) {
            T0 += sredB0[t * 64 + lane];
            T1 += sredB1[t * 64 + lane];
        }
        invS0 = 1.f / T0;
        invS1 = 1.f / T1;
    }

    // ----- conv3d (3x3x3, zero-pad): dual-row, 2 chunks of 8 channels -----
    const float* xb = x + (size_t)b * C_ * HW_;
    #pragma unroll 1
    for (int q = 0; q < 2; ++q) {
        const int c8 = cbase + q * 8;
        float res0[8], res1[8];
        #pragma unroll
        for (int kk = 0; kk < 8; ++kk) { res0[kk] = 0.f; res1[kk] = 0.f; }
        #pragma unroll
        for (int ci = 0; ci < 10; ++ci) {
            const int cc = c8 - 1 + ci;
            const bool cok = (cc >= 0) && (cc < C_);
            #pragma unroll
            for (int jr = 0; jr < 4; ++jr) {
                const int hh = h0 - 1 + jr;
                const bool hok = (hh >= 0) && (hh < H_);
                float v = 0.f;
                if (cok && hok && lane < W_) v = xb[((size_t)cc * H_ + hh) * W_ + lane];
                float vl = __int_as_float(__builtin_amdgcn_mov_dpp(__float_as_int(v), 0x138, 0xf, 0xf, true)); // w-1
                float vr = __int_as_float(__builtin_amdgcn_mov_dpp(__float_as_int(v), 0x130, 0xf, 0xf, true)); // w+1
                vl = (lane == 0) ? 0.f : vl;
                #pragma unroll
                for (int d = 0; d < 3; ++d) {
                    const int kl = ci - 2 + d;          // chunk-local output ch
                    if (kl >= 0 && kl < 8) {
                        const int dc = 2 - d;           // weight channel offset
                        if (jr <= 2) {                  // output row h0, dh=jr
                            const int wi = (dc * 3 + jr) * 3;
                            res0[kl] += W3[wi+0]*vl + W3[wi+1]*v + W3[wi+2]*vr;
                        }
                        if (jr >= 1) {                  // output row h0+1, dh=jr-1
                            const int wi = (dc * 3 + jr - 1) * 3;
                            res1[kl] += W3[wi+0]*vl + W3[wi+1]*v + W3[wi+2]*vr;
                        }
                    }
                }
            }
        }
        // gated residual store (x center re-read: L2-hot; keeps VGPRs low)
        if (lane < W_) {
            #pragma unroll
            for (int kk = 0; kk < 8; ++kk) {
                const int c = c8 + kk;
                const float g0 = bf2f(sg0[c * SGP + lane]) * invS0;
                const float g1 = bf2f(sg1[c * SGP + lane]) * invS1;
                const size_t xi = ((size_t)c * H_ + h0) * W_ + lane;
                const size_t oi = (size_t)b * C_ * HW_ + xi;
                out[oi]      = fmaf(res0[kk], g0, xb[xi]);
                out[oi + W_] = fmaf(res1[kk], g1, xb[xi + W_]);
            }
        }
    }
}

extern "C" void kernel_launch(void* const* d_in, const int* in_sizes, int n_in,
                              void* d_out, int out_size, void* d_ws, size_t ws_size,
                              hipStream_t stream) {
    const float* x  = (const float*)d_in[0];
    const float* Wc = (const float*)d_in[1];
    const float* ac = (const float*)d_in[2];
    const float* Ww = (const float*)d_in[3];
    const float* aw = (const float*)d_in[4];
    const float* Wh = (const float*)d_in[5];
    const float* ah = (const float*)d_in[6];
    const float* W3 = (const float*)d_in[7];
    float* out  = (float*)d_out;
    float* gapc = (float*)d_ws;                 // B*C
    float* gwp  = gapc + B_ * C_;               // B*W (raw sums)
    float* ghp  = gwp + B_ * W_;                // B*H (raw sums)

    hipMemsetAsync(gwp, 0, (size_t)(B_ * W_ + B_ * H_) * sizeof(float), stream);
    k_reduce<<<dim3(B_ * C_), dim3(256), 0, stream>>>(x, gapc, gwp, ghp);
    k_main<<<dim3(B_ * NHT), dim3(1024), 0, stream>>>(
        x, Wc, ac, Ww, aw, Wh, ah, W3, gapc, gwp, ghp, out);
}

// Round 8
// 249.964 us; speedup vs baseline: 1.7053x; 1.7053x over previous
//
#include <hip/hip_runtime.h>

typedef float f32x4 __attribute__((ext_vector_type(4)));
typedef short s16x8 __attribute__((ext_vector_type(8)));
typedef unsigned short ush4 __attribute__((ext_vector_type(4)));

#define B_ 32
#define C_ 256
#define H_ 56
#define W_ 56
#define HW_ (H_*W_)     // 3136
#define CH_ 14336       // C_*H_ == C_*W_
#define NHT 28          // H_/2 row-tiles per batch
#define CPH 68          // ushort stride scout/swout (8B-aligned b64 frag loads)
#define SGP 57          // ushort stride for e-tiles

// LDS layout (73248 B total -> 2 blocks/CU). sg1 aliases scout, sred aliases
// swout: both targets are written only after the last MFMA read (bar2).
#define OFF_SG0   0          // 29184 B (256*57*2)
#define OFF_SCOUT 29184      // 34816 B (256*68*2)  [∪ sg1 29184]
#define OFF_SWOUT 64000      //  8704 B (64*68*2)   [∪ sredB0+sredB1 8192]
#define OFF_SRED0 64000
#define OFF_SRED1 68096
#define OFF_SHOUT 72704      //   544 B (2*68*4)
#define SMEM_SZ   73248

// ---------- helpers ----------
__device__ __forceinline__ unsigned short f2bf(float f) {
    unsigned u = __float_as_uint(f);
    u += 0x7fffu + ((u >> 16) & 1u);     // round-to-nearest-even
    return (unsigned short)(u >> 16);
}
__device__ __forceinline__ float bf2f(unsigned short u) {
    return __uint_as_float((unsigned)u << 16);
}
__device__ __forceinline__ f32x4 bf2f4(ush4 u) {
    f32x4 r; r[0] = bf2f(u[0]); r[1] = bf2f(u[1]); r[2] = bf2f(u[2]); r[3] = bf2f(u[3]);
    return r;
}
__device__ __forceinline__ s16x8 pack8(f32x4 a, f32x4 b) {
    s16x8 r;
    r[0] = (short)f2bf(a[0]); r[1] = (short)f2bf(a[1]);
    r[2] = (short)f2bf(a[2]); r[3] = (short)f2bf(a[3]);
    r[4] = (short)f2bf(b[0]); r[5] = (short)f2bf(b[1]);
    r[6] = (short)f2bf(b[2]); r[7] = (short)f2bf(b[3]);
    return r;
}
__device__ __forceinline__ s16x8 cat8(ush4 a, ush4 b) {
    s16x8 r;
    r[0] = (short)a[0]; r[1] = (short)a[1]; r[2] = (short)a[2]; r[3] = (short)a[3];
    r[4] = (short)b[0]; r[5] = (short)b[1]; r[6] = (short)b[2]; r[7] = (short)b[3];
    return r;
}

// ---------- K1: GAP reductions ----------
__global__ __launch_bounds__(256) void k_reduce(const float* __restrict__ x,
                                                float* __restrict__ gapc,
                                                float* __restrict__ gw,
                                                float* __restrict__ gh) {
    const int b = blockIdx.x >> 8;
    const int c = blockIdx.x & 255;
    const float* px = x + (size_t)(b * C_ + c) * HW_;
    __shared__ float sp[HW_];
    __shared__ float spart[4];
    const int tid = threadIdx.x;
    float tot = 0.f;
    for (int j = tid; j < HW_ / 4; j += 256) {
        f32x4 v = *(const f32x4*)(px + j * 4);
        *(f32x4*)&sp[j * 4] = v;
        tot += v[0] + v[1] + v[2] + v[3];
    }
    for (int d = 32; d > 0; d >>= 1) tot += __shfl_xor(tot, d, 64);
    const int lane = tid & 63, wid = tid >> 6;
    if (lane == 0) spart[wid] = tot;
    __syncthreads();
    if (tid == 0)
        gapc[b * C_ + c] = (spart[0] + spart[1] + spart[2] + spart[3]) * (1.f / HW_);
    if (tid < W_) {
        float s = 0.f;
        for (int h = 0; h < H_; ++h) s += sp[h * W_ + tid];
        atomicAdd(&gw[b * W_ + tid], s);
    } else if (tid >= 64 && tid < 64 + H_) {
        const int h = tid - 64;
        float s = 0.f;
        for (int w = 0; w < W_; ++w) s += sp[h * W_ + w];
        atomicAdd(&gh[b * H_ + h], s);
    }
}

// ---------- K3: fused CP-reconstruct + softmax + conv3d gate ----------
// Merged-row pass (4 barriers), pure-sum softmax (logits ~1e-6: no max sub),
// LDS aliasing -> 73 KB -> 2 blocks/CU, XCD-swizzled block ids.
// Conv: dual-row but 4-channel chunks -> res0[4]+res1[4]=8 live accumulators,
// the footprint round 6 proved spill-free at the allocator's VGPR=32 pin.
__global__ __launch_bounds__(1024)
__attribute__((amdgpu_waves_per_eu(8)))
void k_main(
    const float* __restrict__ x,
    const float* __restrict__ Wc, const float* __restrict__ acp,
    const float* __restrict__ Ww, const float* __restrict__ awp,
    const float* __restrict__ Wh, const float* __restrict__ ahp,
    const float* __restrict__ W3,
    const float* __restrict__ gapc, const float* __restrict__ gw,
    const float* __restrict__ gh,
    float* __restrict__ out)
{
    __shared__ __align__(16) char smem[SMEM_SZ];
    unsigned short* sg0   = (unsigned short*)(smem + OFF_SG0);
    unsigned short* scout = (unsigned short*)(smem + OFF_SCOUT);
    unsigned short* sg1   = scout;                          // alias, post-bar2
    unsigned short* swout = (unsigned short*)(smem + OFF_SWOUT);
    float* sredB0 = (float*)(smem + OFF_SRED0);             // alias swout
    float* sredB1 = (float*)(smem + OFF_SRED1);
    float* shout  = (float*)(smem + OFF_SHOUT);

    // swizzled decode: blocks round-robin XCDs; each XCD owns 4 whole batches
    const int bid  = blockIdx.x;
    const int slot = bid >> 3;
    const int b    = (bid & 7) * 4 + slot / NHT;
    const int h0   = (slot % NHT) * 2;

    const int tid  = threadIdx.x;
    const int lane = tid & 63;
    const int wid  = tid >> 6;
    const int g    = lane >> 4;
    const int col  = lane & 15;
    const int lw   = (lane < W_) ? lane : (W_ - 1);
    const float ac = acp[0], aw = awp[0], ah = ahp[0];

    // ----- staging: factor matrices from the GAP results (bf16) -----
    const float* gc = gapc + b * C_;
    for (int idx = tid; idx < C_ * 64; idx += 1024) {
        const int c = idx >> 6, r = idx & 63;
        const float gm = (c >= 1)      ? gc[c - 1] : 0.f;
        const float g0 = gc[c];
        const float gp = (c < C_ - 1)  ? gc[c + 1] : 0.f;
        float v = Wc[r * 3 + 0] * gm + Wc[r * 3 + 1] * g0 + Wc[r * 3 + 2] * gp;
        scout[c * CPH + r] = f2bf((v >= 0.f) ? v : ac * v);
    }
    const float* gwb = gw + b * W_;
    for (int idx = tid; idx < 64 * 64; idx += 1024) {
        const int w = idx >> 6, r = idx & 63;
        float v = 0.f;
        if (w < W_) {
            const float gm = (w >= 1)     ? gwb[w - 1] * (1.f / CH_) : 0.f;
            const float g0 = gwb[w] * (1.f / CH_);
            const float gp = (w < W_ - 1) ? gwb[w + 1] * (1.f / CH_) : 0.f;
            v = Ww[r * 3 + 0] * gm + Ww[r * 3 + 1] * g0 + Ww[r * 3 + 2] * gp;
            v = (v >= 0.f) ? v : aw * v;
        }
        swout[w * CPH + r] = f2bf(v);
    }
    const float* ghb = gh + b * H_;
    if (tid < 2 * 64) {
        const int hr = tid >> 6, r = tid & 63;
        const int h = h0 + hr;
        const float gm = (h >= 1)     ? ghb[h - 1] * (1.f / CH_) : 0.f;
        const float g0 = ghb[h] * (1.f / CH_);
        const float gp = (h < H_ - 1) ? ghb[h + 1] * (1.f / CH_) : 0.f;
        float v = Wh[r * 3 + 0] * gm + Wh[r * 3 + 1] * g0 + Wh[r * 3 + 2] * gp;
        shout[hr * CPH + r] = (v >= 0.f) ? v : ah * v;
    }
    __syncthreads();                                        // bar1

    const int cbase = wid * 16;
    const int crow  = cbase + col;

    // ----- MFMA row0 -----
    f32x4 acc[4];
    #pragma unroll
    for (int t = 0; t < 4; ++t) acc[t] = (f32x4){0,0,0,0};
    #pragma unroll
    for (int kc = 0; kc < 2; ++kc) {
        const int r0 = kc * 32 + g * 4;
        f32x4 ca = bf2f4(*(ush4*)&scout[crow * CPH + r0]);
        f32x4 cb = bf2f4(*(ush4*)&scout[crow * CPH + r0 + 16]);
        f32x4 ha = *(f32x4*)&shout[0 * CPH + r0];
        f32x4 hb = *(f32x4*)&shout[0 * CPH + r0 + 16];
        s16x8 afrag = pack8(ca * ha, cb * hb);
        #pragma unroll
        for (int t = 0; t < 4; ++t)
            acc[t] = __builtin_amdgcn_mfma_f32_16x16x32_bf16(afrag,
                     cat8(*(ush4*)&swout[(t*16+col)*CPH + r0], *(ush4*)&swout[(t*16+col)*CPH + r0 + 16]),
                     acc[t], 0, 0, 0);
    }
    // write e0 = exp(logit) to sg0 (dedicated buffer; readers wait at bar3)
    {
        const int cr = cbase + g * 4;
        #pragma unroll
        for (int t = 0; t < 4; ++t) {
            const int w = t * 16 + col;
            if (w < W_) {
                sg0[(cr + 0) * SGP + w] = f2bf(__expf(acc[t][0]));
                sg0[(cr + 1) * SGP + w] = f2bf(__expf(acc[t][1]));
                sg0[(cr + 2) * SGP + w] = f2bf(__expf(acc[t][2]));
                sg0[(cr + 3) * SGP + w] = f2bf(__expf(acc[t][3]));
            }
        }
    }
    // ----- MFMA row1 -----
    #pragma unroll
    for (int t = 0; t < 4; ++t) acc[t] = (f32x4){0,0,0,0};
    #pragma unroll
    for (int kc = 0; kc < 2; ++kc) {
        const int r0 = kc * 32 + g * 4;
        f32x4 ca = bf2f4(*(ush4*)&scout[crow * CPH + r0]);
        f32x4 cb = bf2f4(*(ush4*)&scout[crow * CPH + r0 + 16]);
        f32x4 ha = *(f32x4*)&shout[1 * CPH + r0];
        f32x4 hb = *(f32x4*)&shout[1 * CPH + r0 + 16];
        s16x8 afrag = pack8(ca * ha, cb * hb);
        #pragma unroll
        for (int t = 0; t < 4; ++t)
            acc[t] = __builtin_amdgcn_mfma_f32_16x16x32_bf16(afrag,
                     cat8(*(ush4*)&swout[(t*16+col)*CPH + r0], *(ush4*)&swout[(t*16+col)*CPH + r0 + 16]),
                     acc[t], 0, 0, 0);
    }
    __syncthreads();                                        // bar2: scout/swout reads done
    {
        const int cr = cbase + g * 4;
        #pragma unroll
        for (int t = 0; t < 4; ++t) {
            const int w = t * 16 + col;
            if (w < W_) {
                sg1[(cr + 0) * SGP + w] = f2bf(__expf(acc[t][0]));
                sg1[(cr + 1) * SGP + w] = f2bf(__expf(acc[t][1]));
                sg1[(cr + 2) * SGP + w] = f2bf(__expf(acc[t][2]));
                sg1[(cr + 3) * SGP + w] = f2bf(__expf(acc[t][3]));
            }
        }
    }
    __syncthreads();                                        // bar3: e-tiles complete

    // ----- softmax denominators (pure sum; logits ~1e-6 so no max needed) -----
    float invS0, invS1;
    {
        float S0 = 0.f, S1 = 0.f;
        #pragma unroll
        for (int k = 0; k < 16; ++k) {
            S0 += bf2f(sg0[(cbase + k) * SGP + lw]);
            S1 += bf2f(sg1[(cbase + k) * SGP + lw]);
        }
        sredB0[wid * 64 + lane] = S0;
        sredB1[wid * 64 + lane] = S1;
        __syncthreads();                                    // bar4
        float T0 = 0.f, T1 = 0.f;
        #pragma unroll
        for (int t = 0; t < 16; ++t) {
            T0 += sredB0[t * 64 + lane];
            T1 += sredB1[t * 64 + lane];
        }
        invS0 = 1.f / T0;
        invS1 = 1.f / T1;
    }

    // ----- conv3d (3x3x3, zero-pad): dual-row, 4 chunks of 4 channels -----
    // res0[4]+res1[4] = 8 live accumulators (round-6-proven footprint);
    // each x row-load feeds 2 output rows x up-to-3 channel taps.
    const float* xb = x + (size_t)b * C_ * HW_;
    #pragma unroll 1
    for (int q = 0; q < 4; ++q) {
        const int c4 = cbase + q * 4;
        float res0[4], res1[4];
        #pragma unroll
        for (int kk = 0; kk < 4; ++kk) { res0[kk] = 0.f; res1[kk] = 0.f; }
        #pragma unroll
        for (int ci = 0; ci < 6; ++ci) {
            const int cc = c4 - 1 + ci;
            const bool cok = (cc >= 0) && (cc < C_);
            #pragma unroll
            for (int jr = 0; jr < 4; ++jr) {
                const int hh = h0 - 1 + jr;
                const bool hok = (hh >= 0) && (hh < H_);
                float v = 0.f;
                if (cok && hok && lane < W_) v = xb[((size_t)cc * H_ + hh) * W_ + lane];
                float vl = __int_as_float(__builtin_amdgcn_mov_dpp(__float_as_int(v), 0x138, 0xf, 0xf, true)); // w-1
                float vr = __int_as_float(__builtin_amdgcn_mov_dpp(__float_as_int(v), 0x130, 0xf, 0xf, true)); // w+1
                vl = (lane == 0) ? 0.f : vl;
                #pragma unroll
                for (int d = 0; d < 3; ++d) {
                    const int kl = ci - 2 + d;          // chunk-local output ch
                    if (kl >= 0 && kl < 4) {
                        const int dc = 2 - d;           // weight dz = cc-co+1
                        if (jr <= 2) {                  // output row h0, dy=jr
                            const int wi = (dc * 3 + jr) * 3;
                            res0[kl] += W3[wi+0]*vl + W3[wi+1]*v + W3[wi+2]*vr;
                        }
                        if (jr >= 1) {                  // output row h0+1, dy=jr-1
                            const int wi = (dc * 3 + jr - 1) * 3;
                            res1[kl] += W3[wi+0]*vl + W3[wi+1]*v + W3[wi+2]*vr;
                        }
                    }
                }
            }
        }
        // gated residual store (x center re-read: L1/L2-hot; keeps VGPRs low)
        if (lane < W_) {
            #pragma unroll
            for (int kk = 0; kk < 4; ++kk) {
                const int c = c4 + kk;
                const float g0 = bf2f(sg0[c * SGP + lane]) * invS0;
                const float g1 = bf2f(sg1[c * SGP + lane]) * invS1;
                const size_t xi = ((size_t)c * H_ + h0) * W_ + lane;
                const size_t oi = (size_t)b * C_ * HW_ + xi;
                out[oi]      = fmaf(res0[kk], g0, xb[xi]);
                out[oi + W_] = fmaf(res1[kk], g1, xb[xi + W_]);
            }
        }
    }
}

extern "C" void kernel_launch(void* const* d_in, const int* in_sizes, int n_in,
                              void* d_out, int out_size, void* d_ws, size_t ws_size,
                              hipStream_t stream) {
    const float* x  = (const float*)d_in[0];
    const float* Wc = (const float*)d_in[1];
    const float* ac = (const float*)d_in[2];
    const float* Ww = (const float*)d_in[3];
    const float* aw = (const float*)d_in[4];
    const float* Wh = (const float*)d_in[5];
    const float* ah = (const float*)d_in[6];
    const float* W3 = (const float*)d_in[7];
    float* out  = (float*)d_out;
    float* gapc = (float*)d_ws;                 // B*C
    float* gwp  = gapc + B_ * C_;               // B*W (raw sums)
    float* ghp  = gwp + B_ * W_;                // B*H (raw sums)

    hipMemsetAsync(gwp, 0, (size_t)(B_ * W_ + B_ * H_) * sizeof(float), stream);
    k_reduce<<<dim3(B_ * C_), dim3(256), 0, stream>>>(x, gapc, gwp, ghp);
    k_main<<<dim3(B_ * NHT), dim3(1024), 0, stream>>>(
        x, Wc, ac, Ww, aw, Wh, ah, W3, gapc, gwp, ghp, out);
}

// Round 9
// 214.587 us; speedup vs baseline: 1.9864x; 1.1649x over previous
//
#include <hip/hip_runtime.h>

typedef float f32x4 __attribute__((ext_vector_type(4)));
typedef short s16x8 __attribute__((ext_vector_type(8)));
typedef unsigned short ush4 __attribute__((ext_vector_type(4)));

#define B_ 32
#define C_ 256
#define H_ 56
#define W_ 56
#define HW_ (H_*W_)     // 3136
#define CH_ 14336       // C_*H_ == C_*W_
#define NHT 28          // H_/2 row-tiles per batch
#define CPH 68          // ushort stride scout/swout (8B-aligned b64 frag loads)
#define SGP 57          // ushort stride for e-tiles

// LDS layout (73248 B total -> 2 blocks/CU). sg1 aliases scout, sred aliases
// swout: both targets are written only after the last MFMA read (bar2).
#define OFF_SG0   0          // 29184 B (256*57*2)
#define OFF_SCOUT 29184      // 34816 B (256*68*2)  [∪ sg1 29184]
#define OFF_SWOUT 64000      //  8704 B (64*68*2)   [∪ sredB0+sredB1 8192]
#define OFF_SRED0 64000
#define OFF_SRED1 68096
#define OFF_SHOUT 72704      //   544 B (2*68*4)
#define SMEM_SZ   73248

// ---------- helpers ----------
__device__ __forceinline__ unsigned short f2bf(float f) {
    unsigned u = __float_as_uint(f);
    u += 0x7fffu + ((u >> 16) & 1u);     // round-to-nearest-even
    return (unsigned short)(u >> 16);
}
__device__ __forceinline__ float bf2f(unsigned short u) {
    return __uint_as_float((unsigned)u << 16);
}
__device__ __forceinline__ f32x4 bf2f4(ush4 u) {
    f32x4 r; r[0] = bf2f(u[0]); r[1] = bf2f(u[1]); r[2] = bf2f(u[2]); r[3] = bf2f(u[3]);
    return r;
}
__device__ __forceinline__ s16x8 pack8(f32x4 a, f32x4 b) {
    s16x8 r;
    r[0] = (short)f2bf(a[0]); r[1] = (short)f2bf(a[1]);
    r[2] = (short)f2bf(a[2]); r[3] = (short)f2bf(a[3]);
    r[4] = (short)f2bf(b[0]); r[5] = (short)f2bf(b[1]);
    r[6] = (short)f2bf(b[2]); r[7] = (short)f2bf(b[3]);
    return r;
}
__device__ __forceinline__ s16x8 cat8(ush4 a, ush4 b) {
    s16x8 r;
    r[0] = (short)a[0]; r[1] = (short)a[1]; r[2] = (short)a[2]; r[3] = (short)a[3];
    r[4] = (short)b[0]; r[5] = (short)b[1]; r[6] = (short)b[2]; r[7] = (short)b[3];
    return r;
}

// ---------- K1: GAP reductions ----------
__global__ __launch_bounds__(256) void k_reduce(const float* __restrict__ x,
                                                float* __restrict__ gapc,
                                                float* __restrict__ gw,
                                                float* __restrict__ gh) {
    const int b = blockIdx.x >> 8;
    const int c = blockIdx.x & 255;
    const float* px = x + (size_t)(b * C_ + c) * HW_;
    __shared__ float sp[HW_];
    __shared__ float spart[4];
    const int tid = threadIdx.x;
    float tot = 0.f;
    for (int j = tid; j < HW_ / 4; j += 256) {
        f32x4 v = *(const f32x4*)(px + j * 4);
        *(f32x4*)&sp[j * 4] = v;
        tot += v[0] + v[1] + v[2] + v[3];
    }
    for (int d = 32; d > 0; d >>= 1) tot += __shfl_xor(tot, d, 64);
    const int lane = tid & 63, wid = tid >> 6;
    if (lane == 0) spart[wid] = tot;
    __syncthreads();
    if (tid == 0)
        gapc[b * C_ + c] = (spart[0] + spart[1] + spart[2] + spart[3]) * (1.f / HW_);
    if (tid < W_) {
        float s = 0.f;
        for (int h = 0; h < H_; ++h) s += sp[h * W_ + tid];
        atomicAdd(&gw[b * W_ + tid], s);
    } else if (tid >= 64 && tid < 64 + H_) {
        const int h = tid - 64;
        float s = 0.f;
        for (int w = 0; w < W_; ++w) s += sp[h * W_ + w];
        atomicAdd(&gh[b * H_ + h], s);
    }
}

// ---------- K3: fused CP-reconstruct + softmax + conv3d gate ----------
// Merged-row pass (4 barriers), pure-sum softmax (logits ~1e-6: no max sub),
// LDS aliasing -> 73 KB -> 2 blocks/CU, XCD-swizzled block ids.
// NOTE: no amdgpu_waves_per_eu attr! With it the allocator pins VGPR=32 and
// spills (r6: 154 MB, r8: 375 MB scratch). Plain launch_bounds(1024) gives
// VGPR=64 (r1), which still permits 8 waves/SIMD = 2 blocks/CU at 73 KB LDS.
__global__ __launch_bounds__(1024)
void k_main(
    const float* __restrict__ x,
    const float* __restrict__ Wc, const float* __restrict__ acp,
    const float* __restrict__ Ww, const float* __restrict__ awp,
    const float* __restrict__ Wh, const float* __restrict__ ahp,
    const float* __restrict__ W3,
    const float* __restrict__ gapc, const float* __restrict__ gw,
    const float* __restrict__ gh,
    float* __restrict__ out)
{
    __shared__ __align__(16) char smem[SMEM_SZ];
    unsigned short* sg0   = (unsigned short*)(smem + OFF_SG0);
    unsigned short* scout = (unsigned short*)(smem + OFF_SCOUT);
    unsigned short* sg1   = scout;                          // alias, post-bar2
    unsigned short* swout = (unsigned short*)(smem + OFF_SWOUT);
    float* sredB0 = (float*)(smem + OFF_SRED0);             // alias swout
    float* sredB1 = (float*)(smem + OFF_SRED1);
    float* shout  = (float*)(smem + OFF_SHOUT);

    // swizzled decode: blocks round-robin XCDs; each XCD owns 4 whole batches
    const int bid  = blockIdx.x;
    const int slot = bid >> 3;
    const int b    = (bid & 7) * 4 + slot / NHT;
    const int h0   = (slot % NHT) * 2;

    const int tid  = threadIdx.x;
    const int lane = tid & 63;
    const int wid  = tid >> 6;
    const int g    = lane >> 4;
    const int col  = lane & 15;
    const int lw   = (lane < W_) ? lane : (W_ - 1);
    const float ac = acp[0], aw = awp[0], ah = ahp[0];

    // ----- staging: factor matrices from the GAP results (bf16) -----
    const float* gc = gapc + b * C_;
    for (int idx = tid; idx < C_ * 64; idx += 1024) {
        const int c = idx >> 6, r = idx & 63;
        const float gm = (c >= 1)      ? gc[c - 1] : 0.f;
        const float g0 = gc[c];
        const float gp = (c < C_ - 1)  ? gc[c + 1] : 0.f;
        float v = Wc[r * 3 + 0] * gm + Wc[r * 3 + 1] * g0 + Wc[r * 3 + 2] * gp;
        scout[c * CPH + r] = f2bf((v >= 0.f) ? v : ac * v);
    }
    const float* gwb = gw + b * W_;
    for (int idx = tid; idx < 64 * 64; idx += 1024) {
        const int w = idx >> 6, r = idx & 63;
        float v = 0.f;
        if (w < W_) {
            const float gm = (w >= 1)     ? gwb[w - 1] * (1.f / CH_) : 0.f;
            const float g0 = gwb[w] * (1.f / CH_);
            const float gp = (w < W_ - 1) ? gwb[w + 1] * (1.f / CH_) : 0.f;
            v = Ww[r * 3 + 0] * gm + Ww[r * 3 + 1] * g0 + Ww[r * 3 + 2] * gp;
            v = (v >= 0.f) ? v : aw * v;
        }
        swout[w * CPH + r] = f2bf(v);
    }
    const float* ghb = gh + b * H_;
    if (tid < 2 * 64) {
        const int hr = tid >> 6, r = tid & 63;
        const int h = h0 + hr;
        const float gm = (h >= 1)     ? ghb[h - 1] * (1.f / CH_) : 0.f;
        const float g0 = ghb[h] * (1.f / CH_);
        const float gp = (h < H_ - 1) ? ghb[h + 1] * (1.f / CH_) : 0.f;
        float v = Wh[r * 3 + 0] * gm + Wh[r * 3 + 1] * g0 + Wh[r * 3 + 2] * gp;
        shout[hr * CPH + r] = (v >= 0.f) ? v : ah * v;
    }
    __syncthreads();                                        // bar1

    const int cbase = wid * 16;
    const int crow  = cbase + col;

    // ----- MFMA row0 -----
    f32x4 acc[4];
    #pragma unroll
    for (int t = 0; t < 4; ++t) acc[t] = (f32x4){0,0,0,0};
    #pragma unroll
    for (int kc = 0; kc < 2; ++kc) {
        const int r0 = kc * 32 + g * 4;
        f32x4 ca = bf2f4(*(ush4*)&scout[crow * CPH + r0]);
        f32x4 cb = bf2f4(*(ush4*)&scout[crow * CPH + r0 + 16]);
        f32x4 ha = *(f32x4*)&shout[0 * CPH + r0];
        f32x4 hb = *(f32x4*)&shout[0 * CPH + r0 + 16];
        s16x8 afrag = pack8(ca * ha, cb * hb);
        #pragma unroll
        for (int t = 0; t < 4; ++t)
            acc[t] = __builtin_amdgcn_mfma_f32_16x16x32_bf16(afrag,
                     cat8(*(ush4*)&swout[(t*16+col)*CPH + r0], *(ush4*)&swout[(t*16+col)*CPH + r0 + 16]),
                     acc[t], 0, 0, 0);
    }
    // write e0 = exp(logit) to sg0 (dedicated buffer; readers wait at bar3)
    {
        const int cr = cbase + g * 4;
        #pragma unroll
        for (int t = 0; t < 4; ++t) {
            const int w = t * 16 + col;
            if (w < W_) {
                sg0[(cr + 0) * SGP + w] = f2bf(__expf(acc[t][0]));
                sg0[(cr + 1) * SGP + w] = f2bf(__expf(acc[t][1]));
                sg0[(cr + 2) * SGP + w] = f2bf(__expf(acc[t][2]));
                sg0[(cr + 3) * SGP + w] = f2bf(__expf(acc[t][3]));
            }
        }
    }
    // ----- MFMA row1 -----
    #pragma unroll
    for (int t = 0; t < 4; ++t) acc[t] = (f32x4){0,0,0,0};
    #pragma unroll
    for (int kc = 0; kc < 2; ++kc) {
        const int r0 = kc * 32 + g * 4;
        f32x4 ca = bf2f4(*(ush4*)&scout[crow * CPH + r0]);
        f32x4 cb = bf2f4(*(ush4*)&scout[crow * CPH + r0 + 16]);
        f32x4 ha = *(f32x4*)&shout[1 * CPH + r0];
        f32x4 hb = *(f32x4*)&shout[1 * CPH + r0 + 16];
        s16x8 afrag = pack8(ca * ha, cb * hb);
        #pragma unroll
        for (int t = 0; t < 4; ++t)
            acc[t] = __builtin_amdgcn_mfma_f32_16x16x32_bf16(afrag,
                     cat8(*(ush4*)&swout[(t*16+col)*CPH + r0], *(ush4*)&swout[(t*16+col)*CPH + r0 + 16]),
                     acc[t], 0, 0, 0);
    }
    __syncthreads();                                        // bar2: scout/swout reads done
    {
        const int cr = cbase + g * 4;
        #pragma unroll
        for (int t = 0; t < 4; ++t) {
            const int w = t * 16 + col;
            if (w < W_) {
                sg1[(cr + 0) * SGP + w] = f2bf(__expf(acc[t][0]));
                sg1[(cr + 1) * SGP + w] = f2bf(__expf(acc[t][1]));
                sg1[(cr + 2) * SGP + w] = f2bf(__expf(acc[t][2]));
                sg1[(cr + 3) * SGP + w] = f2bf(__expf(acc[t][3]));
            }
        }
    }
    __syncthreads();                                        // bar3: e-tiles complete

    // ----- softmax denominators (pure sum; logits ~1e-6 so no max needed) -----
    float invS0, invS1;
    {
        float S0 = 0.f, S1 = 0.f;
        #pragma unroll
        for (int k = 0; k < 16; ++k) {
            S0 += bf2f(sg0[(cbase + k) * SGP + lw]);
            S1 += bf2f(sg1[(cbase + k) * SGP + lw]);
        }
        sredB0[wid * 64 + lane] = S0;
        sredB1[wid * 64 + lane] = S1;
        __syncthreads();                                    // bar4
        float T0 = 0.f, T1 = 0.f;
        #pragma unroll
        for (int t = 0; t < 16; ++t) {
            T0 += sredB0[t * 64 + lane];
            T1 += sredB1[t * 64 + lane];
        }
        invS0 = 1.f / T0;
        invS1 = 1.f / T1;
    }

    // ----- conv3d (3x3x3, zero-pad): dual-row, 4 chunks of 4 channels -----
    // res0[4]+res1[4] = 8 live accumulators; each x row-load feeds 2 output
    // rows x up-to-3 channel taps.
    const float* xb = x + (size_t)b * C_ * HW_;
    #pragma unroll 1
    for (int q = 0; q < 4; ++q) {
        const int c4 = cbase + q * 4;
        float res0[4], res1[4];
        #pragma unroll
        for (int kk = 0; kk < 4; ++kk) { res0[kk] = 0.f; res1[kk] = 0.f; }
        #pragma unroll
        for (int ci = 0; ci < 6; ++ci) {
            const int cc = c4 - 1 + ci;
            const bool cok = (cc >= 0) && (cc < C_);
            #pragma unroll
            for (int jr = 0; jr < 4; ++jr) {
                const int hh = h0 - 1 + jr;
                const bool hok = (hh >= 0) && (hh < H_);
                float v = 0.f;
                if (cok && hok && lane < W_) v = xb[((size_t)cc * H_ + hh) * W_ + lane];
                float vl = __int_as_float(__builtin_amdgcn_mov_dpp(__float_as_int(v), 0x138, 0xf, 0xf, true)); // w-1
                float vr = __int_as_float(__builtin_amdgcn_mov_dpp(__float_as_int(v), 0x130, 0xf, 0xf, true)); // w+1
                vl = (lane == 0) ? 0.f : vl;
                #pragma unroll
                for (int d = 0; d < 3; ++d) {
                    const int kl = ci - 2 + d;          // chunk-local output ch
                    if (kl >= 0 && kl < 4) {
                        const int dc = 2 - d;           // weight dz = cc-co+1
                        if (jr <= 2) {                  // output row h0, dy=jr
                            const int wi = (dc * 3 + jr) * 3;
                            res0[kl] += W3[wi+0]*vl + W3[wi+1]*v + W3[wi+2]*vr;
                        }
                        if (jr >= 1) {                  // output row h0+1, dy=jr-1
                            const int wi = (dc * 3 + jr - 1) * 3;
                            res1[kl] += W3[wi+0]*vl + W3[wi+1]*v + W3[wi+2]*vr;
                        }
                    }
                }
            }
        }
        // gated residual store (x center re-read: L1/L2-hot; keeps VGPRs low)
        if (lane < W_) {
            #pragma unroll
            for (int kk = 0; kk < 4; ++kk) {
                const int c = c4 + kk;
                const float g0 = bf2f(sg0[c * SGP + lane]) * invS0;
                const float g1 = bf2f(sg1[c * SGP + lane]) * invS1;
                const size_t xi = ((size_t)c * H_ + h0) * W_ + lane;
                const size_t oi = (size_t)b * C_ * HW_ + xi;
                out[oi]      = fmaf(res0[kk], g0, xb[xi]);
                out[oi + W_] = fmaf(res1[kk], g1, xb[xi + W_]);
            }
        }
    }
}

extern "C" void kernel_launch(void* const* d_in, const int* in_sizes, int n_in,
                              void* d_out, int out_size, void* d_ws, size_t ws_size,
                              hipStream_t stream) {
    const float* x  = (const float*)d_in[0];
    const float* Wc = (const float*)d_in[1];
    const float* ac = (const float*)d_in[2];
    const float* Ww = (const float*)d_in[3];
    const float* aw = (const float*)d_in[4];
    const float* Wh = (const float*)d_in[5];
    const float* ah = (const float*)d_in[6];
    const float* W3 = (const float*)d_in[7];
    float* out  = (float*)d_out;
    float* gapc = (float*)d_ws;                 // B*C
    float* gwp  = gapc + B_ * C_;               // B*W (raw sums)
    float* ghp  = gwp + B_ * W_;                // B*H (raw sums)

    hipMemsetAsync(gwp, 0, (size_t)(B_ * W_ + B_ * H_) * sizeof(float), stream);
    k_reduce<<<dim3(B_ * C_), dim3(256), 0, stream>>>(x, gapc, gwp, ghp);
    k_main<<<dim3(B_ * NHT), dim3(1024), 0, stream>>>(
        x, Wc, ac, Ww, aw, Wh, ah, W3, gapc, gwp, ghp, out);
}

// Round 10
// 137.042 us; speedup vs baseline: 3.1105x; 1.5659x over previous
//
#include <hip/hip_runtime.h>

typedef float f32x4 __attribute__((ext_vector_type(4)));
typedef short s16x8 __attribute__((ext_vector_type(8)));
typedef unsigned short ush4 __attribute__((ext_vector_type(4)));

#define B_ 32
#define C_ 256
#define H_ 56
#define W_ 56
#define HW_ (H_*W_)     // 3136
#define CH_ 14336       // C_*H_ == C_*W_
#define NHT 28          // H_/2 row-tiles per batch
#define CPH 68          // ushort stride scout/swout (8B-aligned b64 frag loads)
#define SGP 57          // ushort stride for e-tiles

// LDS layout (73248 B -> 2 blocks/CU). sg1 aliases scout; sred0/1 alias swout.
// Aliased targets are written only after bar2 (last MFMA read of scout/swout).
#define OFF_SG0   0          // 29184 B (256*57*2)
#define OFF_SCOUT 29184      // 34816 B (256*68*2)  [∪ sg1]
#define OFF_SWOUT 64000      //  8704 B (64*68*2)   [∪ sred0(4096)+sred1(4096)]
#define OFF_SRED0 64000
#define OFF_SRED1 68096
#define OFF_SHOUT 72704      //   544 B (2*68*4)
#define SMEM_SZ   73248

// ---------- helpers ----------
__device__ __forceinline__ unsigned short f2bf(float f) {
    unsigned u = __float_as_uint(f);
    u += 0x7fffu + ((u >> 16) & 1u);     // round-to-nearest-even
    return (unsigned short)(u >> 16);
}
__device__ __forceinline__ float bf2f(unsigned short u) {
    return __uint_as_float((unsigned)u << 16);
}
__device__ __forceinline__ f32x4 bf2f4(ush4 u) {
    f32x4 r; r[0] = bf2f(u[0]); r[1] = bf2f(u[1]); r[2] = bf2f(u[2]); r[3] = bf2f(u[3]);
    return r;
}
__device__ __forceinline__ s16x8 pack8(f32x4 a, f32x4 b) {
    s16x8 r;
    r[0] = (short)f2bf(a[0]); r[1] = (short)f2bf(a[1]);
    r[2] = (short)f2bf(a[2]); r[3] = (short)f2bf(a[3]);
    r[4] = (short)f2bf(b[0]); r[5] = (short)f2bf(b[1]);
    r[6] = (short)f2bf(b[2]); r[7] = (short)f2bf(b[3]);
    return r;
}
__device__ __forceinline__ s16x8 cat8(ush4 a, ush4 b) {
    s16x8 r;
    r[0] = (short)a[0]; r[1] = (short)a[1]; r[2] = (short)a[2]; r[3] = (short)a[3];
    r[4] = (short)b[0]; r[5] = (short)b[1]; r[6] = (short)b[2]; r[7] = (short)b[3];
    return r;
}

// ---------- K1: GAP reductions ----------
__global__ __launch_bounds__(256) void k_reduce(const float* __restrict__ x,
                                                float* __restrict__ gapc,
                                                float* __restrict__ gw,
                                                float* __restrict__ gh) {
    const int b = blockIdx.x >> 8;
    const int c = blockIdx.x & 255;
    const float* px = x + (size_t)(b * C_ + c) * HW_;
    __shared__ float sp[HW_];
    __shared__ float spart[4];
    const int tid = threadIdx.x;
    float tot = 0.f;
    for (int j = tid; j < HW_ / 4; j += 256) {
        f32x4 v = *(const f32x4*)(px + j * 4);
        *(f32x4*)&sp[j * 4] = v;
        tot += v[0] + v[1] + v[2] + v[3];
    }
    for (int d = 32; d > 0; d >>= 1) tot += __shfl_xor(tot, d, 64);
    const int lane = tid & 63, wid = tid >> 6;
    if (lane == 0) spart[wid] = tot;
    __syncthreads();
    if (tid == 0)
        gapc[b * C_ + c] = (spart[0] + spart[1] + spart[2] + spart[3]) * (1.f / HW_);
    if (tid < W_) {
        float s = 0.f;
        for (int h = 0; h < H_; ++h) s += sp[h * W_ + tid];
        atomicAdd(&gw[b * W_ + tid], s);
    } else if (tid >= 64 && tid < 64 + H_) {
        const int h = tid - 64;
        float s = 0.f;
        for (int w = 0; w < W_; ++w) s += sp[h * W_ + w];
        atomicAdd(&gh[b * H_ + h], s);
    }
}

// ---------- conv3d + gated store (templated on h-boundary) ----------
// Interior path: loads at pc[(h0-1+jr)*W + lw] -> uniform SGPR base per
// channel, jr folds to +0/224/448/672 byte immediates; no exec-mask dance
// (lw clamps lane 56..63 into the row; vr@lane55 forced 0 for W-padding).
template<bool EDGE>
__device__ __forceinline__ void conv_store(
    const float* __restrict__ xb, const float* __restrict__ W3,
    const unsigned short* sg0, const unsigned short* sg1,
    float invS0, float invS1, int h0, int cbase, int lane, int lw,
    float* __restrict__ outb)
{
    #pragma unroll 1
    for (int q = 0; q < 4; ++q) {
        const int c4 = cbase + q * 4;
        float res0[4] = {0,0,0,0}, res1[4] = {0,0,0,0};
        #pragma unroll
        for (int ci = 0; ci < 6; ++ci) {
            const int cc  = c4 - 1 + ci;
            const bool cok = (cc >= 0) && (cc < C_);
            const int ccl = cc < 0 ? 0 : (cc > C_ - 1 ? C_ - 1 : cc);
            const float* pc = xb + (size_t)ccl * HW_ + lw;
            #pragma unroll
            for (int jr = 0; jr < 4; ++jr) {
                float v;
                if (EDGE) {
                    const int hh  = h0 - 1 + jr;
                    const bool hok = (hh >= 0) && (hh < H_);
                    const int hcl = hh < 0 ? 0 : (hh > H_ - 1 ? H_ - 1 : hh);
                    v = pc[hcl * W_];
                    if (!(cok && hok)) v = 0.f;
                } else {
                    v = pc[(h0 - 1 + jr) * W_];
                    if (!cok) v = 0.f;
                }
                float vl = __int_as_float(__builtin_amdgcn_mov_dpp(__float_as_int(v), 0x138, 0xf, 0xf, true)); // w-1
                float vr = __int_as_float(__builtin_amdgcn_mov_dpp(__float_as_int(v), 0x130, 0xf, 0xf, true)); // w+1
                vl = (lane == 0)      ? 0.f : vl;
                vr = (lane == W_ - 1) ? 0.f : vr;       // right zero-pad
                #pragma unroll
                for (int kl = 0; kl < 4; ++kl) {
                    const int dz = ci - kl;             // weight channel offset
                    if (dz >= 0 && dz <= 2) {
                        if (jr <= 2) {                  // output row h0, dy=jr
                            const int wi = (dz * 3 + jr) * 3;
                            res0[kl] = fmaf(W3[wi], vl, fmaf(W3[wi+1], v, fmaf(W3[wi+2], vr, res0[kl])));
                        }
                        if (jr >= 1) {                  // output row h0+1, dy=jr-1
                            const int wi = (dz * 3 + jr - 1) * 3;
                            res1[kl] = fmaf(W3[wi], vl, fmaf(W3[wi+1], v, fmaf(W3[wi+2], vr, res1[kl])));
                        }
                    }
                }
            }
        }
        if (lane < W_) {
            #pragma unroll
            for (int kk = 0; kk < 4; ++kk) {
                const int c = c4 + kk;
                const float g0v = bf2f(sg0[c * SGP + lane]) * invS0;
                const float g1v = bf2f(sg1[c * SGP + lane]) * invS1;
                const size_t xi = ((size_t)c * H_ + h0) * W_ + lane;
                outb[xi]      = fmaf(res0[kk], g0v, xb[xi]);
                outb[xi + W_] = fmaf(res1[kk], g1v, xb[xi + W_]);
            }
        }
    }
}

// ---------- K3: fused CP-reconstruct + softmax + conv3d gate ----------
// 3 barriers. S computed from registers (f32) via 2x shfl_xor butterfly.
__global__ __launch_bounds__(1024)
void k_main(
    const float* __restrict__ x,
    const float* __restrict__ Wc, const float* __restrict__ acp,
    const float* __restrict__ Ww, const float* __restrict__ awp,
    const float* __restrict__ Wh, const float* __restrict__ ahp,
    const float* __restrict__ W3,
    const float* __restrict__ gapc, const float* __restrict__ gw,
    const float* __restrict__ gh,
    float* __restrict__ out)
{
    __shared__ __align__(16) char smem[SMEM_SZ];
    unsigned short* sg0   = (unsigned short*)(smem + OFF_SG0);
    unsigned short* scout = (unsigned short*)(smem + OFF_SCOUT);
    unsigned short* sg1   = scout;                          // alias, post-bar2
    unsigned short* swout = (unsigned short*)(smem + OFF_SWOUT);
    float* sred0 = (float*)(smem + OFF_SRED0);              // alias swout
    float* sred1 = (float*)(smem + OFF_SRED1);
    float* shout = (float*)(smem + OFF_SHOUT);

    // swizzled decode: blocks round-robin XCDs; each XCD owns 4 whole batches
    const int bid  = blockIdx.x;
    const int slot = bid >> 3;
    const int b    = (bid & 7) * 4 + slot / NHT;
    const int h0   = (slot % NHT) * 2;

    const int tid  = threadIdx.x;
    const int lane = tid & 63;
    const int wid  = tid >> 6;
    const int g    = lane >> 4;
    const int col  = lane & 15;
    const int lw   = (lane < W_) ? lane : (W_ - 1);
    const float ac = acp[0], aw = awp[0], ah = ahp[0];

    // ----- staging: factor matrices from the GAP results (bf16) -----
    const float* gc = gapc + b * C_;
    for (int idx = tid; idx < C_ * 64; idx += 1024) {
        const int c = idx >> 6, r = idx & 63;
        const float gm = (c >= 1)      ? gc[c - 1] : 0.f;
        const float g0 = gc[c];
        const float gp = (c < C_ - 1)  ? gc[c + 1] : 0.f;
        float v = Wc[r * 3 + 0] * gm + Wc[r * 3 + 1] * g0 + Wc[r * 3 + 2] * gp;
        scout[c * CPH + r] = f2bf((v >= 0.f) ? v : ac * v);
    }
    const float* gwb = gw + b * W_;
    for (int idx = tid; idx < 64 * 64; idx += 1024) {
        const int w = idx >> 6, r = idx & 63;
        float v = 0.f;
        if (w < W_) {
            const float gm = (w >= 1)     ? gwb[w - 1] * (1.f / CH_) : 0.f;
            const float g0 = gwb[w] * (1.f / CH_);
            const float gp = (w < W_ - 1) ? gwb[w + 1] * (1.f / CH_) : 0.f;
            v = Ww[r * 3 + 0] * gm + Ww[r * 3 + 1] * g0 + Ww[r * 3 + 2] * gp;
            v = (v >= 0.f) ? v : aw * v;
        }
        swout[w * CPH + r] = f2bf(v);
    }
    const float* ghb = gh + b * H_;
    if (tid < 2 * 64) {
        const int hr = tid >> 6, r = tid & 63;
        const int h = h0 + hr;
        const float gm = (h >= 1)     ? ghb[h - 1] * (1.f / CH_) : 0.f;
        const float g0 = ghb[h] * (1.f / CH_);
        const float gp = (h < H_ - 1) ? ghb[h + 1] * (1.f / CH_) : 0.f;
        float v = Wh[r * 3 + 0] * gm + Wh[r * 3 + 1] * g0 + Wh[r * 3 + 2] * gp;
        shout[hr * CPH + r] = (v >= 0.f) ? v : ah * v;
    }
    __syncthreads();                                        // bar1

    const int cbase = wid * 16;
    const int crow  = cbase + col;

    float s0p, s1p;                 // per-lane wave-partial denominators (w=lane)

    // ----- MFMA row0 -----
    {
        f32x4 acc[4];
        #pragma unroll
        for (int t = 0; t < 4; ++t) acc[t] = (f32x4){0,0,0,0};
        #pragma unroll
        for (int kc = 0; kc < 2; ++kc) {
            const int r0 = kc * 32 + g * 4;
            f32x4 ca = bf2f4(*(ush4*)&scout[crow * CPH + r0]);
            f32x4 cb = bf2f4(*(ush4*)&scout[crow * CPH + r0 + 16]);
            f32x4 ha = *(f32x4*)&shout[0 * CPH + r0];
            f32x4 hb = *(f32x4*)&shout[0 * CPH + r0 + 16];
            s16x8 afrag = pack8(ca * ha, cb * hb);
            #pragma unroll
            for (int t = 0; t < 4; ++t)
                acc[t] = __builtin_amdgcn_mfma_f32_16x16x32_bf16(afrag,
                         cat8(*(ush4*)&swout[(t*16+col)*CPH + r0], *(ush4*)&swout[(t*16+col)*CPH + r0 + 16]),
                         acc[t], 0, 0, 0);
        }
        float st[4];
        #pragma unroll
        for (int t = 0; t < 4; ++t) {
            #pragma unroll
            for (int j = 0; j < 4; ++j) acc[t][j] = __expf(acc[t][j]);
            float s = acc[t][0] + acc[t][1] + acc[t][2] + acc[t][3];
            s += __shfl_xor(s, 16, 64);
            s += __shfl_xor(s, 32, 64);
            st[t] = s;              // wave-partial S at w = t*16+col (all g-lanes)
        }
        s0p = (g == 0) ? st[0] : (g == 1) ? st[1] : (g == 2) ? st[2] : st[3]; // w=lane
        const int cr = cbase + g * 4;
        #pragma unroll
        for (int t = 0; t < 4; ++t) {
            const int w = t * 16 + col;
            if (w < W_) {
                sg0[(cr + 0) * SGP + w] = f2bf(acc[t][0]);
                sg0[(cr + 1) * SGP + w] = f2bf(acc[t][1]);
                sg0[(cr + 2) * SGP + w] = f2bf(acc[t][2]);
                sg0[(cr + 3) * SGP + w] = f2bf(acc[t][3]);
            }
        }
    }
    // ----- MFMA row1 -----
    f32x4 acc[4];
    #pragma unroll
    for (int t = 0; t < 4; ++t) acc[t] = (f32x4){0,0,0,0};
    #pragma unroll
    for (int kc = 0; kc < 2; ++kc) {
        const int r0 = kc * 32 + g * 4;
        f32x4 ca = bf2f4(*(ush4*)&scout[crow * CPH + r0]);
        f32x4 cb = bf2f4(*(ush4*)&scout[crow * CPH + r0 + 16]);
        f32x4 ha = *(f32x4*)&shout[1 * CPH + r0];
        f32x4 hb = *(f32x4*)&shout[1 * CPH + r0 + 16];
        s16x8 afrag = pack8(ca * ha, cb * hb);
        #pragma unroll
        for (int t = 0; t < 4; ++t)
            acc[t] = __builtin_amdgcn_mfma_f32_16x16x32_bf16(afrag,
                     cat8(*(ush4*)&swout[(t*16+col)*CPH + r0], *(ush4*)&swout[(t*16+col)*CPH + r0 + 16]),
                     acc[t], 0, 0, 0);
    }
    {
        float st[4];
        #pragma unroll
        for (int t = 0; t < 4; ++t) {
            #pragma unroll
            for (int j = 0; j < 4; ++j) acc[t][j] = __expf(acc[t][j]);
            float s = acc[t][0] + acc[t][1] + acc[t][2] + acc[t][3];
            s += __shfl_xor(s, 16, 64);
            s += __shfl_xor(s, 32, 64);
            st[t] = s;
        }
        s1p = (g == 0) ? st[0] : (g == 1) ? st[1] : (g == 2) ? st[2] : st[3];
    }
    __syncthreads();                                        // bar2: LDS reads of scout/swout done
    {
        const int cr = cbase + g * 4;
        #pragma unroll
        for (int t = 0; t < 4; ++t) {
            const int w = t * 16 + col;
            if (w < W_) {
                sg1[(cr + 0) * SGP + w] = f2bf(acc[t][0]);
                sg1[(cr + 1) * SGP + w] = f2bf(acc[t][1]);
                sg1[(cr + 2) * SGP + w] = f2bf(acc[t][2]);
                sg1[(cr + 3) * SGP + w] = f2bf(acc[t][3]);
            }
        }
        sred0[wid * 64 + lane] = s0p;
        sred1[wid * 64 + lane] = s1p;
    }
    __syncthreads();                                        // bar3

    float invS0, invS1;
    {
        float T0 = 0.f, T1 = 0.f;
        #pragma unroll
        for (int t = 0; t < 16; ++t) {
            T0 += sred0[t * 64 + lane];
            T1 += sred1[t * 64 + lane];
        }
        invS0 = 1.f / T0;
        invS1 = 1.f / T1;
    }

    const float* xb = x + (size_t)b * C_ * HW_;
    float* outb = out + (size_t)b * C_ * HW_;
    if (h0 == 0 || h0 == H_ - 2)
        conv_store<true >(xb, W3, sg0, sg1, invS0, invS1, h0, cbase, lane, lw, outb);
    else
        conv_store<false>(xb, W3, sg0, sg1, invS0, invS1, h0, cbase, lane, lw, outb);
}

extern "C" void kernel_launch(void* const* d_in, const int* in_sizes, int n_in,
                              void* d_out, int out_size, void* d_ws, size_t ws_size,
                              hipStream_t stream) {
    const float* x  = (const float*)d_in[0];
    const float* Wc = (const float*)d_in[1];
    const float* ac = (const float*)d_in[2];
    const float* Ww = (const float*)d_in[3];
    const float* aw = (const float*)d_in[4];
    const float* Wh = (const float*)d_in[5];
    const float* ah = (const float*)d_in[6];
    const float* W3 = (const float*)d_in[7];
    float* out  = (float*)d_out;
    float* gapc = (float*)d_ws;                 // B*C
    float* gwp  = gapc + B_ * C_;               // B*W (raw sums)
    float* ghp  = gwp + B_ * W_;                // B*H (raw sums)

    hipMemsetAsync(gwp, 0, (size_t)(B_ * W_ + B_ * H_) * sizeof(float), stream);
    k_reduce<<<dim3(B_ * C_), dim3(256), 0, stream>>>(x, gapc, gwp, ghp);
    k_main<<<dim3(B_ * NHT), dim3(1024), 0, stream>>>(
        x, Wc, ac, Ww, aw, Wh, ah, W3, gapc, gwp, ghp, out);
}

// Round 11
// 131.790 us; speedup vs baseline: 3.2344x; 1.0398x over previous
//
#include <hip/hip_runtime.h>

typedef float f32x4 __attribute__((ext_vector_type(4)));
typedef short s16x8 __attribute__((ext_vector_type(8)));
typedef unsigned short ush4 __attribute__((ext_vector_type(4)));

#define B_ 32
#define C_ 256
#define H_ 56
#define W_ 56
#define HW_ (H_*W_)     // 3136
#define CH_ 14336       // C_*H_ == C_*W_
#define NHT 28          // H_/2 row-tiles per batch
#define CPH 68          // ushort stride scout/swout (8B-aligned b64 frag loads)
#define SGP 57          // ushort stride for e-tiles
#define CGRP 16         // channels per k_reduce block

// LDS layout (73248 B -> 2 blocks/CU). sg1 aliases scout; sred0/1 alias swout.
#define OFF_SG0   0          // 29184 B (256*57*2)
#define OFF_SCOUT 29184      // 34816 B (256*68*2)  [∪ sg1]
#define OFF_SWOUT 64000      //  8704 B (64*68*2)   [∪ sred0(4096)+sred1(4096)]
#define OFF_SRED0 64000
#define OFF_SRED1 68096
#define OFF_SHOUT 72704      //   544 B (2*68*4)
#define SMEM_SZ   73248

// ---------- helpers ----------
__device__ __forceinline__ unsigned short f2bf(float f) {
    unsigned u = __float_as_uint(f);
    u += 0x7fffu + ((u >> 16) & 1u);     // round-to-nearest-even
    return (unsigned short)(u >> 16);
}
__device__ __forceinline__ float bf2f(unsigned short u) {
    return __uint_as_float((unsigned)u << 16);
}
__device__ __forceinline__ f32x4 bf2f4(ush4 u) {
    f32x4 r; r[0] = bf2f(u[0]); r[1] = bf2f(u[1]); r[2] = bf2f(u[2]); r[3] = bf2f(u[3]);
    return r;
}
__device__ __forceinline__ s16x8 pack8(f32x4 a, f32x4 b) {
    s16x8 r;
    r[0] = (short)f2bf(a[0]); r[1] = (short)f2bf(a[1]);
    r[2] = (short)f2bf(a[2]); r[3] = (short)f2bf(a[3]);
    r[4] = (short)f2bf(b[0]); r[5] = (short)f2bf(b[1]);
    r[6] = (short)f2bf(b[2]); r[7] = (short)f2bf(b[3]);
    return r;
}
__device__ __forceinline__ s16x8 cat8(ush4 a, ush4 b) {
    s16x8 r;
    r[0] = (short)a[0]; r[1] = (short)a[1]; r[2] = (short)a[2]; r[3] = (short)a[3];
    r[4] = (short)b[0]; r[5] = (short)b[1]; r[6] = (short)b[2]; r[7] = (short)b[3];
    return r;
}

// ---------- K1: GAP reductions (hierarchical; 1 global atomic per value per block) ----------
// grid: B_ x (C_/CGRP) blocks of 832 threads (13 waves; 784 active = plane/4).
// Per-thread positional accumulator over CGRP channels -> LDS row/col sums once.
__global__ __launch_bounds__(832) void k_reduce(const float* __restrict__ x,
                                                float* __restrict__ gapc,
                                                float* __restrict__ gw,
                                                float* __restrict__ gh) {
    __shared__ float chanpart[13 * CGRP];
    __shared__ float rowsum[H_];
    __shared__ float colsum[W_];
    const int bid = blockIdx.x;
    const int b  = bid >> 4;
    const int c0 = (bid & 15) * CGRP;
    const int tid = threadIdx.x;
    const int lane = tid & 63, wid = tid >> 6;
    if (tid < H_) rowsum[tid] = 0.f;
    else if (tid >= 64 && tid < 64 + W_) colsum[tid - 64] = 0.f;
    __syncthreads();

    const bool act = tid < 784;
    const int j = act ? tid : 0;
    const float* px = x + (size_t)(b * C_ + c0) * HW_ + j * 4;
    f32x4 posacc = {0, 0, 0, 0};
    #pragma unroll 4
    for (int c = 0; c < CGRP; ++c) {
        f32x4 v = {0, 0, 0, 0};
        if (act) v = *(const f32x4*)(px + (size_t)c * HW_);
        posacc += v;
        float s = v[0] + v[1] + v[2] + v[3];
        #pragma unroll
        for (int d = 1; d < 64; d <<= 1) s += __shfl_xor(s, d, 64);
        if (lane == 0) chanpart[wid * CGRP + c] = s;
    }
    if (act) {
        const int h = j / 14, w4 = j % 14;
        atomicAdd(&rowsum[h], posacc[0] + posacc[1] + posacc[2] + posacc[3]);
        atomicAdd(&colsum[w4 * 4 + 0], posacc[0]);
        atomicAdd(&colsum[w4 * 4 + 1], posacc[1]);
        atomicAdd(&colsum[w4 * 4 + 2], posacc[2]);
        atomicAdd(&colsum[w4 * 4 + 3], posacc[3]);
    }
    __syncthreads();
    if (tid < CGRP) {
        float t = 0.f;
        #pragma unroll
        for (int w = 0; w < 13; ++w) t += chanpart[w * CGRP + tid];
        gapc[b * C_ + c0 + tid] = t * (1.f / HW_);
    } else if (tid >= 64 && tid < 64 + H_) {
        atomicAdd(&gh[b * H_ + (tid - 64)], rowsum[tid - 64]);
    } else if (tid >= 128 && tid < 128 + W_) {
        atomicAdd(&gw[b * W_ + (tid - 128)], colsum[tid - 128]);
    }
}

// ---------- conv3d + gated store (templated on h-boundary) ----------
// All edge masks are WAVE-UNIFORM (cbase,q,ci,h0,jr) -> scalar branches, no
// per-lane clamps/cndmasks. Channel base folds (h0-1)*W so jr loads become
// immediate offsets. lw clamps lanes 56..63 into the row (loads always legal).
template<bool EDGE>
__device__ __forceinline__ void conv_store(
    const float* __restrict__ xb, const float* __restrict__ W3,
    const unsigned short* sg0, const unsigned short* sg1,
    float invS0, float invS1, int h0, int cbase, int lane, int lw,
    float* __restrict__ outb)
{
    #pragma unroll 1
    for (int q = 0; q < 4; ++q) {
        const int c4 = cbase + q * 4;
        float res0[4] = {0,0,0,0}, res1[4] = {0,0,0,0};
        #pragma unroll
        for (int ci = 0; ci < 6; ++ci) {
            const int cc = c4 - 1 + ci;
            if (cc < 0 || cc >= C_) continue;           // wave-uniform skip
            const float* pcb = xb + (size_t)cc * HW_ + (h0 - 1) * W_ + lw;
            #pragma unroll
            for (int jr = 0; jr < 4; ++jr) {
                if (EDGE && (h0 - 1 + jr < 0 || h0 - 1 + jr >= H_)) continue; // uniform
                float v = pcb[jr * W_];
                float vl = __int_as_float(__builtin_amdgcn_mov_dpp(__float_as_int(v), 0x138, 0xf, 0xf, true)); // w-1
                float vr = __int_as_float(__builtin_amdgcn_mov_dpp(__float_as_int(v), 0x130, 0xf, 0xf, true)); // w+1
                vl = (lane == 0)      ? 0.f : vl;
                vr = (lane == W_ - 1) ? 0.f : vr;       // right zero-pad
                #pragma unroll
                for (int kl = 0; kl < 4; ++kl) {
                    const int dz = ci - kl;             // weight channel offset
                    if (dz >= 0 && dz <= 2) {
                        if (jr <= 2) {                  // output row h0, dy=jr
                            const int wi = (dz * 3 + jr) * 3;
                            res0[kl] = fmaf(W3[wi], vl, fmaf(W3[wi+1], v, fmaf(W3[wi+2], vr, res0[kl])));
                        }
                        if (jr >= 1) {                  // output row h0+1, dy=jr-1
                            const int wi = (dz * 3 + jr - 1) * 3;
                            res1[kl] = fmaf(W3[wi], vl, fmaf(W3[wi+1], v, fmaf(W3[wi+2], vr, res1[kl])));
                        }
                    }
                }
            }
        }
        if (lane < W_) {
            #pragma unroll
            for (int kk = 0; kk < 4; ++kk) {
                const int c = c4 + kk;
                const float g0v = bf2f(sg0[c * SGP + lane]) * invS0;
                const float g1v = bf2f(sg1[c * SGP + lane]) * invS1;
                const size_t xi = ((size_t)c * H_ + h0) * W_ + lane;
                outb[xi]      = fmaf(res0[kk], g0v, xb[xi]);
                outb[xi + W_] = fmaf(res1[kk], g1v, xb[xi + W_]);
            }
        }
    }
}

// ---------- K3: fused CP-reconstruct + softmax + conv3d gate ----------
// 3 barriers. S computed from registers (f32) via 2x shfl_xor butterfly.
__global__ __launch_bounds__(1024)
void k_main(
    const float* __restrict__ x,
    const float* __restrict__ Wc, const float* __restrict__ acp,
    const float* __restrict__ Ww, const float* __restrict__ awp,
    const float* __restrict__ Wh, const float* __restrict__ ahp,
    const float* __restrict__ W3,
    const float* __restrict__ gapc, const float* __restrict__ gw,
    const float* __restrict__ gh,
    float* __restrict__ out)
{
    __shared__ __align__(16) char smem[SMEM_SZ];
    unsigned short* sg0   = (unsigned short*)(smem + OFF_SG0);
    unsigned short* scout = (unsigned short*)(smem + OFF_SCOUT);
    unsigned short* sg1   = scout;                          // alias, post-bar2
    unsigned short* swout = (unsigned short*)(smem + OFF_SWOUT);
    float* sred0 = (float*)(smem + OFF_SRED0);              // alias swout
    float* sred1 = (float*)(smem + OFF_SRED1);
    float* shout = (float*)(smem + OFF_SHOUT);

    // swizzled decode: blocks round-robin XCDs; each XCD owns 4 whole batches
    const int bid  = blockIdx.x;
    const int slot = bid >> 3;
    const int b    = (bid & 7) * 4 + slot / NHT;
    const int h0   = (slot % NHT) * 2;

    const int tid  = threadIdx.x;
    const int lane = tid & 63;
    const int wid  = tid >> 6;
    const int g    = lane >> 4;
    const int col  = lane & 15;
    const int lw   = (lane < W_) ? lane : (W_ - 1);
    const float ac = acp[0], aw = awp[0], ah = ahp[0];

    // ----- staging: factor matrices from the GAP results (bf16) -----
    const float* gc = gapc + b * C_;
    for (int idx = tid; idx < C_ * 64; idx += 1024) {
        const int c = idx >> 6, r = idx & 63;
        const float gm = (c >= 1)      ? gc[c - 1] : 0.f;
        const float g0 = gc[c];
        const float gp = (c < C_ - 1)  ? gc[c + 1] : 0.f;
        float v = Wc[r * 3 + 0] * gm + Wc[r * 3 + 1] * g0 + Wc[r * 3 + 2] * gp;
        scout[c * CPH + r] = f2bf((v >= 0.f) ? v : ac * v);
    }
    const float* gwb = gw + b * W_;
    for (int idx = tid; idx < 64 * 64; idx += 1024) {
        const int w = idx >> 6, r = idx & 63;
        float v = 0.f;
        if (w < W_) {
            const float gm = (w >= 1)     ? gwb[w - 1] * (1.f / CH_) : 0.f;
            const float g0 = gwb[w] * (1.f / CH_);
            const float gp = (w < W_ - 1) ? gwb[w + 1] * (1.f / CH_) : 0.f;
            v = Ww[r * 3 + 0] * gm + Ww[r * 3 + 1] * g0 + Ww[r * 3 + 2] * gp;
            v = (v >= 0.f) ? v : aw * v;
        }
        swout[w * CPH + r] = f2bf(v);
    }
    const float* ghb = gh + b * H_;
    if (tid < 2 * 64) {
        const int hr = tid >> 6, r = tid & 63;
        const int h = h0 + hr;
        const float gm = (h >= 1)     ? ghb[h - 1] * (1.f / CH_) : 0.f;
        const float g0 = ghb[h] * (1.f / CH_);
        const float gp = (h < H_ - 1) ? ghb[h + 1] * (1.f / CH_) : 0.f;
        float v = Wh[r * 3 + 0] * gm + Wh[r * 3 + 1] * g0 + Wh[r * 3 + 2] * gp;
        shout[hr * CPH + r] = (v >= 0.f) ? v : ah * v;
    }
    __syncthreads();                                        // bar1

    const int cbase = wid * 16;
    const int crow  = cbase + col;

    float s0p, s1p;                 // per-lane wave-partial denominators (w=lane)

    // ----- MFMA row0 -----
    {
        f32x4 acc[4];
        #pragma unroll
        for (int t = 0; t < 4; ++t) acc[t] = (f32x4){0,0,0,0};
        #pragma unroll
        for (int kc = 0; kc < 2; ++kc) {
            const int r0 = kc * 32 + g * 4;
            f32x4 ca = bf2f4(*(ush4*)&scout[crow * CPH + r0]);
            f32x4 cb = bf2f4(*(ush4*)&scout[crow * CPH + r0 + 16]);
            f32x4 ha = *(f32x4*)&shout[0 * CPH + r0];
            f32x4 hb = *(f32x4*)&shout[0 * CPH + r0 + 16];
            s16x8 afrag = pack8(ca * ha, cb * hb);
            #pragma unroll
            for (int t = 0; t < 4; ++t)
                acc[t] = __builtin_amdgcn_mfma_f32_16x16x32_bf16(afrag,
                         cat8(*(ush4*)&swout[(t*16+col)*CPH + r0], *(ush4*)&swout[(t*16+col)*CPH + r0 + 16]),
                         acc[t], 0, 0, 0);
        }
        float st[4];
        #pragma unroll
        for (int t = 0; t < 4; ++t) {
            #pragma unroll
            for (int j = 0; j < 4; ++j) acc[t][j] = __expf(acc[t][j]);
            float s = acc[t][0] + acc[t][1] + acc[t][2] + acc[t][3];
            s += __shfl_xor(s, 16, 64);
            s += __shfl_xor(s, 32, 64);
            st[t] = s;              // wave-partial S at w = t*16+col (all g-lanes)
        }
        s0p = (g == 0) ? st[0] : (g == 1) ? st[1] : (g == 2) ? st[2] : st[3]; // w=lane
        const int cr = cbase + g * 4;
        #pragma unroll
        for (int t = 0; t < 4; ++t) {
            const int w = t * 16 + col;
            if (w < W_) {
                sg0[(cr + 0) * SGP + w] = f2bf(acc[t][0]);
                sg0[(cr + 1) * SGP + w] = f2bf(acc[t][1]);
                sg0[(cr + 2) * SGP + w] = f2bf(acc[t][2]);
                sg0[(cr + 3) * SGP + w] = f2bf(acc[t][3]);
            }
        }
    }
    // ----- MFMA row1 -----
    f32x4 acc[4];
    #pragma unroll
    for (int t = 0; t < 4; ++t) acc[t] = (f32x4){0,0,0,0};
    #pragma unroll
    for (int kc = 0; kc < 2; ++kc) {
        const int r0 = kc * 32 + g * 4;
        f32x4 ca = bf2f4(*(ush4*)&scout[crow * CPH + r0]);
        f32x4 cb = bf2f4(*(ush4*)&scout[crow * CPH + r0 + 16]);
        f32x4 ha = *(f32x4*)&shout[1 * CPH + r0];
        f32x4 hb = *(f32x4*)&shout[1 * CPH + r0 + 16];
        s16x8 afrag = pack8(ca * ha, cb * hb);
        #pragma unroll
        for (int t = 0; t < 4; ++t)
            acc[t] = __builtin_amdgcn_mfma_f32_16x16x32_bf16(afrag,
                     cat8(*(ush4*)&swout[(t*16+col)*CPH + r0], *(ush4*)&swout[(t*16+col)*CPH + r0 + 16]),
                     acc[t], 0, 0, 0);
    }
    {
        float st[4];
        #pragma unroll
        for (int t = 0; t < 4; ++t) {
            #pragma unroll
            for (int j = 0; j < 4; ++j) acc[t][j] = __expf(acc[t][j]);
            float s = acc[t][0] + acc[t][1] + acc[t][2] + acc[t][3];
            s += __shfl_xor(s, 16, 64);
            s += __shfl_xor(s, 32, 64);
            st[t] = s;
        }
        s1p = (g == 0) ? st[0] : (g == 1) ? st[1] : (g == 2) ? st[2] : st[3];
    }
    __syncthreads();                                        // bar2: LDS reads of scout/swout done
    {
        const int cr = cbase + g * 4;
        #pragma unroll
        for (int t = 0; t < 4; ++t) {
            const int w = t * 16 + col;
            if (w < W_) {
                sg1[(cr + 0) * SGP + w] = f2bf(acc[t][0]);
                sg1[(cr + 1) * SGP + w] = f2bf(acc[t][1]);
                sg1[(cr + 2) * SGP + w] = f2bf(acc[t][2]);
                sg1[(cr + 3) * SGP + w] = f2bf(acc[t][3]);
            }
        }
        sred0[wid * 64 + lane] = s0p;
        sred1[wid * 64 + lane] = s1p;
    }
    __syncthreads();                                        // bar3

    float invS0, invS1;
    {
        float T0 = 0.f, T1 = 0.f;
        #pragma unroll
        for (int t = 0; t < 16; ++t) {
            T0 += sred0[t * 64 + lane];
            T1 += sred1[t * 64 + lane];
        }
        invS0 = 1.f / T0;
        invS1 = 1.f / T1;
    }

    const float* xb = x + (size_t)b * C_ * HW_;
    float* outb = out + (size_t)b * C_ * HW_;
    if (h0 == 0 || h0 == H_ - 2)
        conv_store<true >(xb, W3, sg0, sg1, invS0, invS1, h0, cbase, lane, lw, outb);
    else
        conv_store<false>(xb, W3, sg0, sg1, invS0, invS1, h0, cbase, lane, lw, outb);
}

extern "C" void kernel_launch(void* const* d_in, const int* in_sizes, int n_in,
                              void* d_out, int out_size, void* d_ws, size_t ws_size,
                              hipStream_t stream) {
    const float* x  = (const float*)d_in[0];
    const float* Wc = (const float*)d_in[1];
    const float* ac = (const float*)d_in[2];
    const float* Ww = (const float*)d_in[3];
    const float* aw = (const float*)d_in[4];
    const float* Wh = (const float*)d_in[5];
    const float* ah = (const float*)d_in[6];
    const float* W3 = (const float*)d_in[7];
    float* out  = (float*)d_out;
    float* gapc = (float*)d_ws;                 // B*C
    float* gwp  = gapc + B_ * C_;               // B*W (raw sums)
    float* ghp  = gwp + B_ * W_;                // B*H (raw sums)

    hipMemsetAsync(gwp, 0, (size_t)(B_ * W_ + B_ * H_) * sizeof(float), stream);
    k_reduce<<<dim3(B_ * (C_ / CGRP)), dim3(832), 0, stream>>>(x, gapc, gwp, ghp);
    k_main<<<dim3(B_ * NHT), dim3(1024), 0, stream>>>(
        x, Wc, ac, Ww, aw, Wh, ah, W3, gapc, gwp, ghp, out);
}

// Round 12
// 121.476 us; speedup vs baseline: 3.5090x; 1.0849x over previous
//
#include <hip/hip_runtime.h>

typedef float f32x4 __attribute__((ext_vector_type(4)));
typedef short s16x8 __attribute__((ext_vector_type(8)));
typedef unsigned short ush4 __attribute__((ext_vector_type(4)));

#define B_ 32
#define C_ 256
#define H_ 56
#define W_ 56
#define HW_ (H_*W_)     // 3136
#define CH_ 14336       // C_*H_ == C_*W_
#define NHT 28          // H_/2 row-tiles per batch
#define CPH 68          // ushort stride scout/swout (8B-aligned b64 frag loads)
#define SGP 57          // ushort stride for e-tiles
#define CGRP 16         // channels per k_reduce block

// LDS layout (73248 B -> 2 blocks/CU). sg1 aliases scout; sred0/1 alias swout.
#define OFF_SG0   0          // 29184 B (256*57*2)
#define OFF_SCOUT 29184      // 34816 B (256*68*2)  [∪ sg1]
#define OFF_SWOUT 64000      //  8704 B (64*68*2)   [∪ sred0(4096)+sred1(4096)]
#define OFF_SRED0 64000
#define OFF_SRED1 68096
#define OFF_SHOUT 72704      //   544 B (2*68*4)
#define SMEM_SZ   73248

// ---------- helpers ----------
__device__ __forceinline__ unsigned short f2bf(float f) {
    unsigned u = __float_as_uint(f);
    u += 0x7fffu + ((u >> 16) & 1u);     // round-to-nearest-even
    return (unsigned short)(u >> 16);
}
__device__ __forceinline__ float bf2f(unsigned short u) {
    return __uint_as_float((unsigned)u << 16);
}
__device__ __forceinline__ f32x4 bf2f4(ush4 u) {
    f32x4 r; r[0] = bf2f(u[0]); r[1] = bf2f(u[1]); r[2] = bf2f(u[2]); r[3] = bf2f(u[3]);
    return r;
}
__device__ __forceinline__ s16x8 pack8(f32x4 a, f32x4 b) {
    s16x8 r;
    r[0] = (short)f2bf(a[0]); r[1] = (short)f2bf(a[1]);
    r[2] = (short)f2bf(a[2]); r[3] = (short)f2bf(a[3]);
    r[4] = (short)f2bf(b[0]); r[5] = (short)f2bf(b[1]);
    r[6] = (short)f2bf(b[2]); r[7] = (short)f2bf(b[3]);
    return r;
}
__device__ __forceinline__ s16x8 cat8(ush4 a, ush4 b) {
    s16x8 r;
    r[0] = (short)a[0]; r[1] = (short)a[1]; r[2] = (short)a[2]; r[3] = (short)a[3];
    r[4] = (short)b[0]; r[5] = (short)b[1]; r[6] = (short)b[2]; r[7] = (short)b[3];
    return r;
}

// ---------- K1: GAP reductions (hierarchical; 1 global atomic per value per block) ----------
__global__ __launch_bounds__(832) void k_reduce(const float* __restrict__ x,
                                                float* __restrict__ gapc,
                                                float* __restrict__ gw,
                                                float* __restrict__ gh) {
    __shared__ float chanpart[13 * CGRP];
    __shared__ float rowsum[H_];
    __shared__ float colsum[W_];
    const int bid = blockIdx.x;
    const int b  = bid >> 4;
    const int c0 = (bid & 15) * CGRP;
    const int tid = threadIdx.x;
    const int lane = tid & 63, wid = tid >> 6;
    if (tid < H_) rowsum[tid] = 0.f;
    else if (tid >= 64 && tid < 64 + W_) colsum[tid - 64] = 0.f;
    __syncthreads();

    const bool act = tid < 784;
    const int j = act ? tid : 0;
    const float* px = x + (size_t)(b * C_ + c0) * HW_ + j * 4;
    f32x4 posacc = {0, 0, 0, 0};
    #pragma unroll 4
    for (int c = 0; c < CGRP; ++c) {
        f32x4 v = {0, 0, 0, 0};
        if (act) v = *(const f32x4*)(px + (size_t)c * HW_);
        posacc += v;
        float s = v[0] + v[1] + v[2] + v[3];
        #pragma unroll
        for (int d = 1; d < 64; d <<= 1) s += __shfl_xor(s, d, 64);
        if (lane == 0) chanpart[wid * CGRP + c] = s;
    }
    if (act) {
        const int h = j / 14, w4 = j % 14;
        atomicAdd(&rowsum[h], posacc[0] + posacc[1] + posacc[2] + posacc[3]);
        atomicAdd(&colsum[w4 * 4 + 0], posacc[0]);
        atomicAdd(&colsum[w4 * 4 + 1], posacc[1]);
        atomicAdd(&colsum[w4 * 4 + 2], posacc[2]);
        atomicAdd(&colsum[w4 * 4 + 3], posacc[3]);
    }
    __syncthreads();
    if (tid < CGRP) {
        float t = 0.f;
        #pragma unroll
        for (int w = 0; w < 13; ++w) t += chanpart[w * CGRP + tid];
        gapc[b * C_ + c0 + tid] = t * (1.f / HW_);
    } else if (tid >= 64 && tid < 64 + H_) {
        atomicAdd(&gh[b * H_ + (tid - 64)], rowsum[tid - 64]);
    } else if (tid >= 128 && tid < 128 + W_) {
        atomicAdd(&gw[b * W_ + (tid - 128)], colsum[tid - 128]);
    }
}

// ---------- conv3d + gated store (templated on h-boundary) ----------
// BRANCH-FREE body (round-10 form, proven fastest): clamped addresses +
// cndmask zeroing; all 24 loads of a chunk can issue back-to-back (MLP).
// Residual center rows captured in-loop (xm0/xm1) -> no xb re-read at store.
template<bool EDGE>
__device__ __forceinline__ void conv_store(
    const float* __restrict__ xb, const float* __restrict__ W3,
    const unsigned short* sg0, const unsigned short* sg1,
    float invS0, float invS1, int h0, int cbase, int lane, int lw,
    float* __restrict__ outb)
{
    #pragma unroll 1
    for (int q = 0; q < 4; ++q) {
        const int c4 = cbase + q * 4;
        float res0[4] = {0,0,0,0}, res1[4] = {0,0,0,0};
        float xm0[4], xm1[4];
        #pragma unroll
        for (int ci = 0; ci < 6; ++ci) {
            const int cc  = c4 - 1 + ci;
            const bool cok = (cc >= 0) && (cc < C_);
            const int ccl = cc < 0 ? 0 : (cc > C_ - 1 ? C_ - 1 : cc);
            const float* pc = xb + (size_t)ccl * HW_ + lw;
            #pragma unroll
            for (int jr = 0; jr < 4; ++jr) {
                float v;
                if (EDGE) {
                    const int hh  = h0 - 1 + jr;
                    const bool hok = (hh >= 0) && (hh < H_);
                    const int hcl = hh < 0 ? 0 : (hh > H_ - 1 ? H_ - 1 : hh);
                    v = pc[hcl * W_];
                    if (!(cok && hok)) v = 0.f;
                } else {
                    v = pc[(h0 - 1 + jr) * W_];
                    if (!cok) v = 0.f;
                }
                // residual capture: center channel (cc==c4+ci-1), rows h0/h0+1
                if (ci >= 1 && ci <= 4) {
                    if (jr == 1) xm0[ci - 1] = v;
                    if (jr == 2) xm1[ci - 1] = v;
                }
                float vl = __int_as_float(__builtin_amdgcn_mov_dpp(__float_as_int(v), 0x138, 0xf, 0xf, true)); // w-1
                float vr = __int_as_float(__builtin_amdgcn_mov_dpp(__float_as_int(v), 0x130, 0xf, 0xf, true)); // w+1
                vl = (lane == 0)      ? 0.f : vl;
                vr = (lane == W_ - 1) ? 0.f : vr;       // right zero-pad
                #pragma unroll
                for (int kl = 0; kl < 4; ++kl) {
                    const int dz = ci - kl;             // weight channel offset
                    if (dz >= 0 && dz <= 2) {
                        if (jr <= 2) {                  // output row h0, dy=jr
                            const int wi = (dz * 3 + jr) * 3;
                            res0[kl] = fmaf(W3[wi], vl, fmaf(W3[wi+1], v, fmaf(W3[wi+2], vr, res0[kl])));
                        }
                        if (jr >= 1) {                  // output row h0+1, dy=jr-1
                            const int wi = (dz * 3 + jr - 1) * 3;
                            res1[kl] = fmaf(W3[wi], vl, fmaf(W3[wi+1], v, fmaf(W3[wi+2], vr, res1[kl])));
                        }
                    }
                }
            }
        }
        if (lane < W_) {
            #pragma unroll
            for (int kk = 0; kk < 4; ++kk) {
                const int c = c4 + kk;
                const float g0v = bf2f(sg0[c * SGP + lane]) * invS0;
                const float g1v = bf2f(sg1[c * SGP + lane]) * invS1;
                const size_t xi = ((size_t)c * H_ + h0) * W_ + lane;
                outb[xi]      = fmaf(res0[kk], g0v, xm0[kk]);
                outb[xi + W_] = fmaf(res1[kk], g1v, xm1[kk]);
            }
        }
    }
}

// ---------- K3: fused CP-reconstruct + softmax + conv3d gate ----------
// 3 barriers. S computed from registers (f32) via 2x shfl_xor butterfly.
__global__ __launch_bounds__(1024)
void k_main(
    const float* __restrict__ x,
    const float* __restrict__ Wc, const float* __restrict__ acp,
    const float* __restrict__ Ww, const float* __restrict__ awp,
    const float* __restrict__ Wh, const float* __restrict__ ahp,
    const float* __restrict__ W3,
    const float* __restrict__ gapc, const float* __restrict__ gw,
    const float* __restrict__ gh,
    float* __restrict__ out)
{
    __shared__ __align__(16) char smem[SMEM_SZ];
    unsigned short* sg0   = (unsigned short*)(smem + OFF_SG0);
    unsigned short* scout = (unsigned short*)(smem + OFF_SCOUT);
    unsigned short* sg1   = scout;                          // alias, post-bar2
    unsigned short* swout = (unsigned short*)(smem + OFF_SWOUT);
    float* sred0 = (float*)(smem + OFF_SRED0);              // alias swout
    float* sred1 = (float*)(smem + OFF_SRED1);
    float* shout = (float*)(smem + OFF_SHOUT);

    // swizzled decode: blocks round-robin XCDs; each XCD owns 4 whole batches
    const int bid  = blockIdx.x;
    const int slot = bid >> 3;
    const int b    = (bid & 7) * 4 + slot / NHT;
    const int h0   = (slot % NHT) * 2;

    const int tid  = threadIdx.x;
    const int lane = tid & 63;
    const int wid  = tid >> 6;
    const int g    = lane >> 4;
    const int col  = lane & 15;
    const int lw   = (lane < W_) ? lane : (W_ - 1);
    const float ac = acp[0], aw = awp[0], ah = ahp[0];

    // ----- staging: factor matrices from the GAP results (bf16) -----
    const float* gc = gapc + b * C_;
    for (int idx = tid; idx < C_ * 64; idx += 1024) {
        const int c = idx >> 6, r = idx & 63;
        const float gm = (c >= 1)      ? gc[c - 1] : 0.f;
        const float g0 = gc[c];
        const float gp = (c < C_ - 1)  ? gc[c + 1] : 0.f;
        float v = Wc[r * 3 + 0] * gm + Wc[r * 3 + 1] * g0 + Wc[r * 3 + 2] * gp;
        scout[c * CPH + r] = f2bf((v >= 0.f) ? v : ac * v);
    }
    const float* gwb = gw + b * W_;
    for (int idx = tid; idx < 64 * 64; idx += 1024) {
        const int w = idx >> 6, r = idx & 63;
        float v = 0.f;
        if (w < W_) {
            const float gm = (w >= 1)     ? gwb[w - 1] * (1.f / CH_) : 0.f;
            const float g0 = gwb[w] * (1.f / CH_);
            const float gp = (w < W_ - 1) ? gwb[w + 1] * (1.f / CH_) : 0.f;
            v = Ww[r * 3 + 0] * gm + Ww[r * 3 + 1] * g0 + Ww[r * 3 + 2] * gp;
            v = (v >= 0.f) ? v : aw * v;
        }
        swout[w * CPH + r] = f2bf(v);
    }
    const float* ghb = gh + b * H_;
    if (tid < 2 * 64) {
        const int hr = tid >> 6, r = tid & 63;
        const int h = h0 + hr;
        const float gm = (h >= 1)     ? ghb[h - 1] * (1.f / CH_) : 0.f;
        const float g0 = ghb[h] * (1.f / CH_);
        const float gp = (h < H_ - 1) ? ghb[h + 1] * (1.f / CH_) : 0.f;
        float v = Wh[r * 3 + 0] * gm + Wh[r * 3 + 1] * g0 + Wh[r * 3 + 2] * gp;
        shout[hr * CPH + r] = (v >= 0.f) ? v : ah * v;
    }
    __syncthreads();                                        // bar1

    const int cbase = wid * 16;
    const int crow  = cbase + col;

    float s0p, s1p;                 // per-lane wave-partial denominators (w=lane)

    // ----- MFMA row0 -----
    {
        f32x4 acc[4];
        #pragma unroll
        for (int t = 0; t < 4; ++t) acc[t] = (f32x4){0,0,0,0};
        #pragma unroll
        for (int kc = 0; kc < 2; ++kc) {
            const int r0 = kc * 32 + g * 4;
            f32x4 ca = bf2f4(*(ush4*)&scout[crow * CPH + r0]);
            f32x4 cb = bf2f4(*(ush4*)&scout[crow * CPH + r0 + 16]);
            f32x4 ha = *(f32x4*)&shout[0 * CPH + r0];
            f32x4 hb = *(f32x4*)&shout[0 * CPH + r0 + 16];
            s16x8 afrag = pack8(ca * ha, cb * hb);
            #pragma unroll
            for (int t = 0; t < 4; ++t)
                acc[t] = __builtin_amdgcn_mfma_f32_16x16x32_bf16(afrag,
                         cat8(*(ush4*)&swout[(t*16+col)*CPH + r0], *(ush4*)&swout[(t*16+col)*CPH + r0 + 16]),
                         acc[t], 0, 0, 0);
        }
        float st[4];
        #pragma unroll
        for (int t = 0; t < 4; ++t) {
            #pragma unroll
            for (int j = 0; j < 4; ++j) acc[t][j] = __expf(acc[t][j]);
            float s = acc[t][0] + acc[t][1] + acc[t][2] + acc[t][3];
            s += __shfl_xor(s, 16, 64);
            s += __shfl_xor(s, 32, 64);
            st[t] = s;              // wave-partial S at w = t*16+col (all g-lanes)
        }
        s0p = (g == 0) ? st[0] : (g == 1) ? st[1] : (g == 2) ? st[2] : st[3]; // w=lane
        const int cr = cbase + g * 4;
        #pragma unroll
        for (int t = 0; t < 4; ++t) {
            const int w = t * 16 + col;
            if (w < W_) {
                sg0[(cr + 0) * SGP + w] = f2bf(acc[t][0]);
                sg0[(cr + 1) * SGP + w] = f2bf(acc[t][1]);
                sg0[(cr + 2) * SGP + w] = f2bf(acc[t][2]);
                sg0[(cr + 3) * SGP + w] = f2bf(acc[t][3]);
            }
        }
    }
    // ----- MFMA row1 -----
    f32x4 acc[4];
    #pragma unroll
    for (int t = 0; t < 4; ++t) acc[t] = (f32x4){0,0,0,0};
    #pragma unroll
    for (int kc = 0; kc < 2; ++kc) {
        const int r0 = kc * 32 + g * 4;
        f32x4 ca = bf2f4(*(ush4*)&scout[crow * CPH + r0]);
        f32x4 cb = bf2f4(*(ush4*)&scout[crow * CPH + r0 + 16]);
        f32x4 ha = *(f32x4*)&shout[1 * CPH + r0];
        f32x4 hb = *(f32x4*)&shout[1 * CPH + r0 + 16];
        s16x8 afrag = pack8(ca * ha, cb * hb);
        #pragma unroll
        for (int t = 0; t < 4; ++t)
            acc[t] = __builtin_amdgcn_mfma_f32_16x16x32_bf16(afrag,
                     cat8(*(ush4*)&swout[(t*16+col)*CPH + r0], *(ush4*)&swout[(t*16+col)*CPH + r0 + 16]),
                     acc[t], 0, 0, 0);
    }
    {
        float st[4];
        #pragma unroll
        for (int t = 0; t < 4; ++t) {
            #pragma unroll
            for (int j = 0; j < 4; ++j) acc[t][j] = __expf(acc[t][j]);
            float s = acc[t][0] + acc[t][1] + acc[t][2] + acc[t][3];
            s += __shfl_xor(s, 16, 64);
            s += __shfl_xor(s, 32, 64);
            st[t] = s;
        }
        s1p = (g == 0) ? st[0] : (g == 1) ? st[1] : (g == 2) ? st[2] : st[3];
    }
    __syncthreads();                                        // bar2: LDS reads of scout/swout done
    {
        const int cr = cbase + g * 4;
        #pragma unroll
        for (int t = 0; t < 4; ++t) {
            const int w = t * 16 + col;
            if (w < W_) {
                sg1[(cr + 0) * SGP + w] = f2bf(acc[t][0]);
                sg1[(cr + 1) * SGP + w] = f2bf(acc[t][1]);
                sg1[(cr + 2) * SGP + w] = f2bf(acc[t][2]);
                sg1[(cr + 3) * SGP + w] = f2bf(acc[t][3]);
            }
        }
        sred0[wid * 64 + lane] = s0p;
        sred1[wid * 64 + lane] = s1p;
    }
    __syncthreads();                                        // bar3

    float invS0, invS1;
    {
        float T0 = 0.f, T1 = 0.f;
        #pragma unroll
        for (int t = 0; t < 16; ++t) {
            T0 += sred0[t * 64 + lane];
            T1 += sred1[t * 64 + lane];
        }
        invS0 = 1.f / T0;
        invS1 = 1.f / T1;
    }

    const float* xb = x + (size_t)b * C_ * HW_;
    float* outb = out + (size_t)b * C_ * HW_;
    if (h0 == 0 || h0 == H_ - 2)
        conv_store<true >(xb, W3, sg0, sg1, invS0, invS1, h0, cbase, lane, lw, outb);
    else
        conv_store<false>(xb, W3, sg0, sg1, invS0, invS1, h0, cbase, lane, lw, outb);
}

extern "C" void kernel_launch(void* const* d_in, const int* in_sizes, int n_in,
                              void* d_out, int out_size, void* d_ws, size_t ws_size,
                              hipStream_t stream) {
    const float* x  = (const float*)d_in[0];
    const float* Wc = (const float*)d_in[1];
    const float* ac = (const float*)d_in[2];
    const float* Ww = (const float*)d_in[3];
    const float* aw = (const float*)d_in[4];
    const float* Wh = (const float*)d_in[5];
    const float* ah = (const float*)d_in[6];
    const float* W3 = (const float*)d_in[7];
    float* out  = (float*)d_out;
    float* gapc = (float*)d_ws;                 // B*C
    float* gwp  = gapc + B_ * C_;               // B*W (raw sums)
    float* ghp  = gwp + B_ * W_;                // B*H (raw sums)

    hipMemsetAsync(gwp, 0, (size_t)(B_ * W_ + B_ * H_) * sizeof(float), stream);
    k_reduce<<<dim3(B_ * (C_ / CGRP)), dim3(832), 0, stream>>>(x, gapc, gwp, ghp);
    k_main<<<dim3(B_ * NHT), dim3(1024), 0, stream>>>(
        x, Wc, ac, Ww, aw, Wh, ah, W3, gapc, gwp, ghp, out);
}

// Round 14
// 117.570 us; speedup vs baseline: 3.6256x; 1.0332x over previous
//
#include <hip/hip_runtime.h>
#include <hip/hip_bf16.h>

typedef float f32x4 __attribute__((ext_vector_type(4)));
typedef short s16x8 __attribute__((ext_vector_type(8)));
typedef unsigned short ush4 __attribute__((ext_vector_type(4)));
typedef unsigned u32x4 __attribute__((ext_vector_type(4)));
typedef unsigned u32x2 __attribute__((ext_vector_type(2)));

#define B_ 32
#define C_ 256
#define H_ 56
#define W_ 56
#define HW_ (H_*W_)     // 3136
#define CH_ 14336       // C_*H_ == C_*W_
#define NHT 28          // H_/2 row-tiles per batch
#define CPH 68          // ushort stride scout/swout (8B-aligned b64 frag loads)
#define SGPT 260        // ushort stride for TRANSPOSED gate tiles [w][c] (520B/row)
#define CGRP 16         // channels per k_reduce block

// LDS layout (73184 B -> 2 blocks/CU). sg1T aliases scout; sred0/1 alias swout.
#define OFF_SG0T  0          // 29120 B (56*260*2)
#define OFF_SCOUT 29120      // 34816 B (256*68*2)  [∪ sg1T 29120]
#define OFF_SWOUT 63936      //  8704 B (64*68*2)   [∪ sred0(4096)+sred1(4096)]
#define OFF_SRED0 63936
#define OFF_SRED1 68032
#define OFF_SHOUT 72640      //   544 B (2*68*4)
#define SMEM_SZ   73184

// ---------- helpers ----------
__device__ __forceinline__ unsigned short f2bf(float f) {
    unsigned u = __float_as_uint(f);
    u += 0x7fffu + ((u >> 16) & 1u);     // round-to-nearest-even
    return (unsigned short)(u >> 16);
}
__device__ __forceinline__ float bf2f(unsigned short u) {
    return __uint_as_float((unsigned)u << 16);
}
__device__ __forceinline__ f32x4 bf2f4(ush4 u) {
    f32x4 r; r[0] = bf2f(u[0]); r[1] = bf2f(u[1]); r[2] = bf2f(u[2]); r[3] = bf2f(u[3]);
    return r;
}
// pair-pack via intrinsic so the compiler emits v_cvt_pk_bf16_f32 (m240: do
// NOT hand-write the asm form). low word = first operand. bit_cast rejected
// __hip_bfloat162 (non-trivially-copyable) -> memcpy-based reinterpretation.
__device__ __forceinline__ unsigned pkbf(float lo, float hi) {
    __hip_bfloat162 h = __float22bfloat162_rn(make_float2(lo, hi));
    unsigned r;
    __builtin_memcpy(&r, &h, 4);
    return r;
}
__device__ __forceinline__ s16x8 pack8(f32x4 a, f32x4 b) {
    u32x4 t = { pkbf(a[0], a[1]), pkbf(a[2], a[3]), pkbf(b[0], b[1]), pkbf(b[2], b[3]) };
    s16x8 r;
    __builtin_memcpy(&r, &t, 16);
    return r;
}
__device__ __forceinline__ s16x8 cat8(ush4 a, ush4 b) {
    s16x8 r;
    r[0] = (short)a[0]; r[1] = (short)a[1]; r[2] = (short)a[2]; r[3] = (short)a[3];
    r[4] = (short)b[0]; r[5] = (short)b[1]; r[6] = (short)b[2]; r[7] = (short)b[3];
    return r;
}
__device__ __forceinline__ float dpp_shr1(float v) {   // lane i <- v[i-1]; lane0 <- 0 (bound_ctrl)
    return __int_as_float(__builtin_amdgcn_mov_dpp(__float_as_int(v), 0x138, 0xf, 0xf, true));
}
__device__ __forceinline__ float dpp_shl1(float v) {   // lane i <- v[i+1]; lane63 <- 0
    return __int_as_float(__builtin_amdgcn_mov_dpp(__float_as_int(v), 0x130, 0xf, 0xf, true));
}

// ---------- K1: GAP reductions (hierarchical; 1 global atomic per value per block) ----------
__global__ __launch_bounds__(832) void k_reduce(const float* __restrict__ x,
                                                float* __restrict__ gapc,
                                                float* __restrict__ gw,
                                                float* __restrict__ gh) {
    __shared__ float chanpart[13 * CGRP];
    __shared__ float rowsum[H_];
    __shared__ float colsum[W_];
    const int bid = blockIdx.x;
    const int b  = bid >> 4;
    const int c0 = (bid & 15) * CGRP;
    const int tid = threadIdx.x;
    const int lane = tid & 63, wid = tid >> 6;
    if (tid < H_) rowsum[tid] = 0.f;
    else if (tid >= 64 && tid < 64 + W_) colsum[tid - 64] = 0.f;
    __syncthreads();

    const bool act = tid < 784;
    const int j = act ? tid : 0;
    const float* px = x + (size_t)(b * C_ + c0) * HW_ + j * 4;
    f32x4 posacc = {0, 0, 0, 0};
    #pragma unroll 4
    for (int c = 0; c < CGRP; ++c) {
        f32x4 v = {0, 0, 0, 0};
        if (act) v = *(const f32x4*)(px + (size_t)c * HW_);
        posacc += v;
        float s = v[0] + v[1] + v[2] + v[3];
        #pragma unroll
        for (int d = 1; d < 64; d <<= 1) s += __shfl_xor(s, d, 64);
        if (lane == 0) chanpart[wid * CGRP + c] = s;
    }
    if (act) {
        const int h = j / 14, w4 = j % 14;
        atomicAdd(&rowsum[h], posacc[0] + posacc[1] + posacc[2] + posacc[3]);
        atomicAdd(&colsum[w4 * 4 + 0], posacc[0]);
        atomicAdd(&colsum[w4 * 4 + 1], posacc[1]);
        atomicAdd(&colsum[w4 * 4 + 2], posacc[2]);
        atomicAdd(&colsum[w4 * 4 + 3], posacc[3]);
    }
    __syncthreads();
    if (tid < CGRP) {
        float t = 0.f;
        #pragma unroll
        for (int w = 0; w < 13; ++w) t += chanpart[w * CGRP + tid];
        gapc[b * C_ + c0 + tid] = t * (1.f / HW_);
    } else if (tid >= 64 && tid < 64 + H_) {
        atomicAdd(&gh[b * H_ + (tid - 64)], rowsum[tid - 64]);
    } else if (tid >= 128 && tid < 128 + W_) {
        atomicAdd(&gw[b * W_ + (tid - 128)], colsum[tid - 128]);
    }
}

// ---------- conv3d + gated store (templated on h-boundary) ----------
// Branch-free body; masks minimized: v zeroed once (combined cok/hok/lane<W),
// vl lane-0 zero comes free from DPP bound_ctrl, vr lane-55 zero comes from
// v[56..63]==0. Gates read as one b64 (4 channels) from transposed sg tiles.
template<bool EDGE>
__device__ __forceinline__ void conv_store(
    const float* __restrict__ xb, const float* __restrict__ W3,
    const unsigned short* sg0, const unsigned short* sg1,
    float invS0, float invS1, int h0, int cbase, int lane, int lw,
    float* __restrict__ outb)
{
    #pragma unroll 1
    for (int q = 0; q < 4; ++q) {
        const int c4 = cbase + q * 4;
        float res0[4] = {0,0,0,0}, res1[4] = {0,0,0,0};
        float xm0[4], xm1[4];
        #pragma unroll
        for (int ci = 0; ci < 6; ++ci) {
            const int cc  = c4 - 1 + ci;
            const bool cok = (cc >= 0) && (cc < C_);
            const int ccl = cc < 0 ? 0 : (cc > C_ - 1 ? C_ - 1 : cc);
            const float* pc = xb + (size_t)ccl * HW_ + lw;
            #pragma unroll
            for (int jr = 0; jr < 4; ++jr) {
                float v;
                bool keep = cok && (lane < W_);
                if (EDGE) {
                    const int hh  = h0 - 1 + jr;
                    keep = keep && (hh >= 0) && (hh < H_);
                    const int hcl = hh < 0 ? 0 : (hh > H_ - 1 ? H_ - 1 : hh);
                    v = pc[hcl * W_];
                } else {
                    v = pc[(h0 - 1 + jr) * W_];
                }
                v = keep ? v : 0.f;
                // residual capture: center channel (cc==c4+ci-1), rows h0/h0+1
                if (ci >= 1 && ci <= 4) {
                    if (jr == 1) xm0[ci - 1] = v;
                    if (jr == 2) xm1[ci - 1] = v;
                }
                const float vl = dpp_shr1(v);           // lane0 -> 0 (bound_ctrl)
                const float vr = dpp_shl1(v);           // lane55 -> v[56]==0
                #pragma unroll
                for (int kl = 0; kl < 4; ++kl) {
                    const int dz = ci - kl;             // weight channel offset
                    if (dz >= 0 && dz <= 2) {
                        if (jr <= 2) {                  // output row h0, dy=jr
                            const int wi = (dz * 3 + jr) * 3;
                            res0[kl] = fmaf(W3[wi], vl, fmaf(W3[wi+1], v, fmaf(W3[wi+2], vr, res0[kl])));
                        }
                        if (jr >= 1) {                  // output row h0+1, dy=jr-1
                            const int wi = (dz * 3 + jr - 1) * 3;
                            res1[kl] = fmaf(W3[wi], vl, fmaf(W3[wi+1], v, fmaf(W3[wi+2], vr, res1[kl])));
                        }
                    }
                }
            }
        }
        if (lane < W_) {
            const ush4 q0 = *(const ush4*)&sg0[lane * SGPT + c4];   // 4 gates, one b64
            const ush4 q1 = *(const ush4*)&sg1[lane * SGPT + c4];
            #pragma unroll
            for (int kk = 0; kk < 4; ++kk) {
                const int c = c4 + kk;
                const size_t xi = ((size_t)c * H_ + h0) * W_ + lane;
                outb[xi]      = fmaf(res0[kk], bf2f(q0[kk]) * invS0, xm0[kk]);
                outb[xi + W_] = fmaf(res1[kk], bf2f(q1[kk]) * invS1, xm1[kk]);
            }
        }
    }
}

// ---------- K3: fused CP-reconstruct + softmax + conv3d gate ----------
// 3 barriers. S from registers (f32 butterfly). Gate tiles TRANSPOSED [w][c]:
// logit writes are b64 (4 ch/op), conv gate reads are b64; banks conflict-free.
__global__ __launch_bounds__(1024)
void k_main(
    const float* __restrict__ x,
    const float* __restrict__ Wc, const float* __restrict__ acp,
    const float* __restrict__ Ww, const float* __restrict__ awp,
    const float* __restrict__ Wh, const float* __restrict__ ahp,
    const float* __restrict__ W3,
    const float* __restrict__ gapc, const float* __restrict__ gw,
    const float* __restrict__ gh,
    float* __restrict__ out)
{
    __shared__ __align__(16) char smem[SMEM_SZ];
    unsigned short* sg0   = (unsigned short*)(smem + OFF_SG0T);
    unsigned short* scout = (unsigned short*)(smem + OFF_SCOUT);
    unsigned short* sg1   = scout;                          // alias, post-bar2
    unsigned short* swout = (unsigned short*)(smem + OFF_SWOUT);
    float* sred0 = (float*)(smem + OFF_SRED0);              // alias swout
    float* sred1 = (float*)(smem + OFF_SRED1);
    float* shout = (float*)(smem + OFF_SHOUT);

    // swizzled decode: blocks round-robin XCDs; each XCD owns 4 whole batches
    const int bid  = blockIdx.x;
    const int slot = bid >> 3;
    const int b    = (bid & 7) * 4 + slot / NHT;
    const int h0   = (slot % NHT) * 2;

    const int tid  = threadIdx.x;
    const int lane = tid & 63;
    const int wid  = tid >> 6;
    const int g    = lane >> 4;
    const int col  = lane & 15;
    const int lw   = (lane < W_) ? lane : (W_ - 1);
    const float ac = acp[0], aw = awp[0], ah = ahp[0];

    // ----- staging: factor matrices from the GAP results (bf16) -----
    const float* gc = gapc + b * C_;
    for (int idx = tid; idx < C_ * 64; idx += 1024) {
        const int c = idx >> 6, r = idx & 63;
        const float gm = (c >= 1)      ? gc[c - 1] : 0.f;
        const float g0 = gc[c];
        const float gp = (c < C_ - 1)  ? gc[c + 1] : 0.f;
        float v = Wc[r * 3 + 0] * gm + Wc[r * 3 + 1] * g0 + Wc[r * 3 + 2] * gp;
        scout[c * CPH + r] = f2bf((v >= 0.f) ? v : ac * v);
    }
    const float* gwb = gw + b * W_;
    for (int idx = tid; idx < 64 * 64; idx += 1024) {
        const int w = idx >> 6, r = idx & 63;
        float v = 0.f;
        if (w < W_) {
            const float gm = (w >= 1)     ? gwb[w - 1] * (1.f / CH_) : 0.f;
            const float g0 = gwb[w] * (1.f / CH_);
            const float gp = (w < W_ - 1) ? gwb[w + 1] * (1.f / CH_) : 0.f;
            v = Ww[r * 3 + 0] * gm + Ww[r * 3 + 1] * g0 + Ww[r * 3 + 2] * gp;
            v = (v >= 0.f) ? v : aw * v;
        }
        swout[w * CPH + r] = f2bf(v);
    }
    const float* ghb = gh + b * H_;
    if (tid < 2 * 64) {
        const int hr = tid >> 6, r = tid & 63;
        const int h = h0 + hr;
        const float gm = (h >= 1)     ? ghb[h - 1] * (1.f / CH_) : 0.f;
        const float g0 = ghb[h] * (1.f / CH_);
        const float gp = (h < H_ - 1) ? ghb[h + 1] * (1.f / CH_) : 0.f;
        float v = Wh[r * 3 + 0] * gm + Wh[r * 3 + 1] * g0 + Wh[r * 3 + 2] * gp;
        shout[hr * CPH + r] = (v >= 0.f) ? v : ah * v;
    }
    __syncthreads();                                        // bar1

    const int cbase = wid * 16;
    const int crow  = cbase + col;
    const int cr    = cbase + g * 4;

    float s0p, s1p;                 // per-lane wave-partial denominators (w=lane)

    // ----- MFMA row0 -----
    {
        f32x4 acc[4];
        #pragma unroll
        for (int t = 0; t < 4; ++t) acc[t] = (f32x4){0,0,0,0};
        #pragma unroll
        for (int kc = 0; kc < 2; ++kc) {
            const int r0 = kc * 32 + g * 4;
            f32x4 ca = bf2f4(*(ush4*)&scout[crow * CPH + r0]);
            f32x4 cb = bf2f4(*(ush4*)&scout[crow * CPH + r0 + 16]);
            f32x4 ha = *(f32x4*)&shout[0 * CPH + r0];
            f32x4 hb = *(f32x4*)&shout[0 * CPH + r0 + 16];
            s16x8 afrag = pack8(ca * ha, cb * hb);
            #pragma unroll
            for (int t = 0; t < 4; ++t)
                acc[t] = __builtin_amdgcn_mfma_f32_16x16x32_bf16(afrag,
                         cat8(*(ush4*)&swout[(t*16+col)*CPH + r0], *(ush4*)&swout[(t*16+col)*CPH + r0 + 16]),
                         acc[t], 0, 0, 0);
        }
        float st[4];
        #pragma unroll
        for (int t = 0; t < 4; ++t) {
            #pragma unroll
            for (int j = 0; j < 4; ++j) acc[t][j] = __expf(acc[t][j]);
            float s = acc[t][0] + acc[t][1] + acc[t][2] + acc[t][3];
            s += __shfl_xor(s, 16, 64);
            s += __shfl_xor(s, 32, 64);
            st[t] = s;              // wave-partial S at w = t*16+col (all g-lanes)
        }
        s0p = (g == 0) ? st[0] : (g == 1) ? st[1] : (g == 2) ? st[2] : st[3]; // w=lane
        #pragma unroll
        for (int t = 0; t < 4; ++t) {
            const int w = t * 16 + col;
            if (w < W_) {
                u32x2 pkd = { pkbf(acc[t][0], acc[t][1]), pkbf(acc[t][2], acc[t][3]) };
                *(u32x2*)&sg0[w * SGPT + cr] = pkd;     // [w][cr..cr+3], one b64
            }
        }
    }
    // ----- MFMA row1 -----
    f32x4 acc[4];
    #pragma unroll
    for (int t = 0; t < 4; ++t) acc[t] = (f32x4){0,0,0,0};
    #pragma unroll
    for (int kc = 0; kc < 2; ++kc) {
        const int r0 = kc * 32 + g * 4;
        f32x4 ca = bf2f4(*(ush4*)&scout[crow * CPH + r0]);
        f32x4 cb = bf2f4(*(ush4*)&scout[crow * CPH + r0 + 16]);
        f32x4 ha = *(f32x4*)&shout[1 * CPH + r0];
        f32x4 hb = *(f32x4*)&shout[1 * CPH + r0 + 16];
        s16x8 afrag = pack8(ca * ha, cb * hb);
        #pragma unroll
        for (int t = 0; t < 4; ++t)
            acc[t] = __builtin_amdgcn_mfma_f32_16x16x32_bf16(afrag,
                     cat8(*(ush4*)&swout[(t*16+col)*CPH + r0], *(ush4*)&swout[(t*16+col)*CPH + r0 + 16]),
                     acc[t], 0, 0, 0);
    }
    {
        float st[4];
        #pragma unroll
        for (int t = 0; t < 4; ++t) {
            #pragma unroll
            for (int j = 0; j < 4; ++j) acc[t][j] = __expf(acc[t][j]);
            float s = acc[t][0] + acc[t][1] + acc[t][2] + acc[t][3];
            s += __shfl_xor(s, 16, 64);
            s += __shfl_xor(s, 32, 64);
            st[t] = s;
        }
        s1p = (g == 0) ? st[0] : (g == 1) ? st[1] : (g == 2) ? st[2] : st[3];
    }
    __syncthreads();                                        // bar2: LDS reads of scout/swout done
    {
        #pragma unroll
        for (int t = 0; t < 4; ++t) {
            const int w = t * 16 + col;
            if (w < W_) {
                u32x2 pkd = { pkbf(acc[t][0], acc[t][1]), pkbf(acc[t][2], acc[t][3]) };
                *(u32x2*)&sg1[w * SGPT + cr] = pkd;
            }
        }
        sred0[wid * 64 + lane] = s0p;
        sred1[wid * 64 + lane] = s1p;
    }
    __syncthreads();                                        // bar3

    float invS0, invS1;
    {
        float T0 = 0.f, T1 = 0.f;
        #pragma unroll
        for (int t = 0; t < 16; ++t) {
            T0 += sred0[t * 64 + lane];
            T1 += sred1[t * 64 + lane];
        }
        invS0 = 1.f / T0;
        invS1 = 1.f / T1;
    }

    const float* xb = x + (size_t)b * C_ * HW_;
    float* outb = out + (size_t)b * C_ * HW_;
    if (h0 == 0 || h0 == H_ - 2)
        conv_store<true >(xb, W3, sg0, sg1, invS0, invS1, h0, cbase, lane, lw, outb);
    else
        conv_store<false>(xb, W3, sg0, sg1, invS0, invS1, h0, cbase, lane, lw, outb);
}

extern "C" void kernel_launch(void* const* d_in, const int* in_sizes, int n_in,
                              void* d_out, int out_size, void* d_ws, size_t ws_size,
                              hipStream_t stream) {
    const float* x  = (const float*)d_in[0];
    const float* Wc = (const float*)d_in[1];
    const float* ac = (const float*)d_in[2];
    const float* Ww = (const float*)d_in[3];
    const float* aw = (const float*)d_in[4];
    const float* Wh = (const float*)d_in[5];
    const float* ah = (const float*)d_in[6];
    const float* W3 = (const float*)d_in[7];
    float* out  = (float*)d_out;
    float* gapc = (float*)d_ws;                 // B*C
    float* gwp  = gapc + B_ * C_;               // B*W (raw sums)
    float* ghp  = gwp + B_ * W_;                // B*H (raw sums)

    (void)hipMemsetAsync(gwp, 0, (size_t)(B_ * W_ + B_ * H_) * sizeof(float), stream);
    k_reduce<<<dim3(B_ * (C_ / CGRP)), dim3(832), 0, stream>>>(x, gapc, gwp, ghp);
    k_main<<<dim3(B_ * NHT), dim3(1024), 0, stream>>>(
        x, Wc, ac, Ww, aw, Wh, ah, W3, gapc, gwp, ghp, out);
}

// Round 15
// 107.981 us; speedup vs baseline: 3.9476x; 1.0888x over previous
//
#include <hip/hip_runtime.h>
#include <hip/hip_bf16.h>

typedef float f32x4 __attribute__((ext_vector_type(4)));
typedef short s16x8 __attribute__((ext_vector_type(8)));
typedef unsigned short ush4 __attribute__((ext_vector_type(4)));
typedef unsigned u32x4 __attribute__((ext_vector_type(4)));
typedef unsigned u32x2 __attribute__((ext_vector_type(2)));

#define B_ 32
#define C_ 256
#define H_ 56
#define W_ 56
#define HW_ (H_*W_)     // 3136
#define CH_ 14336       // C_*H_ == C_*W_
#define NHT 28          // H_/2 row-tiles per batch
#define CPH 68          // ushort stride scout/swout (8B-aligned b64 frag loads)
#define SGPT 260        // ushort stride for TRANSPOSED gate tiles [w][c] (520B/row)
#define CGRP 16         // channels per k_reduce block

// LDS layout (73184 B -> 2 blocks/CU). sg1T aliases scout; sred0/1 alias swout.
#define OFF_SG0T  0          // 29120 B (56*260*2)
#define OFF_SCOUT 29120      // 34816 B (256*68*2)  [∪ sg1T 29120]
#define OFF_SWOUT 63936      //  8704 B (64*68*2)   [∪ sred0(4096)+sred1(4096)]
#define OFF_SRED0 63936
#define OFF_SRED1 68032
#define OFF_SHOUT 72640      //   544 B (2*68*4)
#define SMEM_SZ   73184

// ---------- helpers ----------
__device__ __forceinline__ unsigned short f2bf(float f) {
    unsigned u = __float_as_uint(f);
    u += 0x7fffu + ((u >> 16) & 1u);     // round-to-nearest-even
    return (unsigned short)(u >> 16);
}
__device__ __forceinline__ float bf2f(unsigned short u) {
    return __uint_as_float((unsigned)u << 16);
}
__device__ __forceinline__ f32x4 bf2f4(ush4 u) {
    f32x4 r; r[0] = bf2f(u[0]); r[1] = bf2f(u[1]); r[2] = bf2f(u[2]); r[3] = bf2f(u[3]);
    return r;
}
// pair-pack via intrinsic so the compiler emits v_cvt_pk_bf16_f32 (m240: do
// NOT hand-write the asm form). low word = first operand.
__device__ __forceinline__ unsigned pkbf(float lo, float hi) {
    __hip_bfloat162 h = __float22bfloat162_rn(make_float2(lo, hi));
    unsigned r;
    __builtin_memcpy(&r, &h, 4);
    return r;
}
__device__ __forceinline__ s16x8 pack8(f32x4 a, f32x4 b) {
    u32x4 t = { pkbf(a[0], a[1]), pkbf(a[2], a[3]), pkbf(b[0], b[1]), pkbf(b[2], b[3]) };
    s16x8 r;
    __builtin_memcpy(&r, &t, 16);
    return r;
}
__device__ __forceinline__ s16x8 cat8(ush4 a, ush4 b) {
    s16x8 r;
    r[0] = (short)a[0]; r[1] = (short)a[1]; r[2] = (short)a[2]; r[3] = (short)a[3];
    r[4] = (short)b[0]; r[5] = (short)b[1]; r[6] = (short)b[2]; r[7] = (short)b[3];
    return r;
}
__device__ __forceinline__ float dpp_shr1(float v) {   // lane i <- v[i-1]; lane0 <- 0 (bound_ctrl)
    return __int_as_float(__builtin_amdgcn_mov_dpp(__float_as_int(v), 0x138, 0xf, 0xf, true));
}
__device__ __forceinline__ float dpp_shl1(float v) {   // lane i <- v[i+1]; lane63 <- 0
    return __int_as_float(__builtin_amdgcn_mov_dpp(__float_as_int(v), 0x130, 0xf, 0xf, true));
}

// ---------- K1: GAP reductions (hierarchical; 1 global atomic per value per block) ----------
__global__ __launch_bounds__(832) void k_reduce(const float* __restrict__ x,
                                                float* __restrict__ gapc,
                                                float* __restrict__ gw,
                                                float* __restrict__ gh) {
    __shared__ float chanpart[13 * CGRP];
    __shared__ float rowsum[H_];
    __shared__ float colsum[W_];
    const int bid = blockIdx.x;
    const int b  = bid >> 4;
    const int c0 = (bid & 15) * CGRP;
    const int tid = threadIdx.x;
    const int lane = tid & 63, wid = tid >> 6;
    if (tid < H_) rowsum[tid] = 0.f;
    else if (tid >= 64 && tid < 64 + W_) colsum[tid - 64] = 0.f;
    __syncthreads();

    const bool act = tid < 784;
    const int j = act ? tid : 0;
    const float* px = x + (size_t)(b * C_ + c0) * HW_ + j * 4;
    f32x4 posacc = {0, 0, 0, 0};
    #pragma unroll 4
    for (int c = 0; c < CGRP; ++c) {
        f32x4 v = {0, 0, 0, 0};
        if (act) v = *(const f32x4*)(px + (size_t)c * HW_);
        posacc += v;
        float s = v[0] + v[1] + v[2] + v[3];
        #pragma unroll
        for (int d = 1; d < 64; d <<= 1) s += __shfl_xor(s, d, 64);
        if (lane == 0) chanpart[wid * CGRP + c] = s;
    }
    if (act) {
        const int h = j / 14, w4 = j % 14;
        atomicAdd(&rowsum[h], posacc[0] + posacc[1] + posacc[2] + posacc[3]);
        atomicAdd(&colsum[w4 * 4 + 0], posacc[0]);
        atomicAdd(&colsum[w4 * 4 + 1], posacc[1]);
        atomicAdd(&colsum[w4 * 4 + 2], posacc[2]);
        atomicAdd(&colsum[w4 * 4 + 3], posacc[3]);
    }
    __syncthreads();
    if (tid < CGRP) {
        float t = 0.f;
        #pragma unroll
        for (int w = 0; w < 13; ++w) t += chanpart[w * CGRP + tid];
        gapc[b * C_ + c0 + tid] = t * (1.f / HW_);
    } else if (tid >= 64 && tid < 64 + H_) {
        atomicAdd(&gh[b * H_ + (tid - 64)], rowsum[tid - 64]);
    } else if (tid >= 128 && tid < 128 + W_) {
        atomicAdd(&gw[b * W_ + (tid - 128)], colsum[tid - 128]);
    }
}

// ---------- conv3d + gated store (templated on h-boundary) ----------
template<bool EDGE>
__device__ __forceinline__ void conv_store(
    const float* __restrict__ xb, const float* __restrict__ W3,
    const unsigned short* sg0, const unsigned short* sg1,
    float invS0, float invS1, int h0, int cbase, int lane, int lw,
    float* __restrict__ outb)
{
    #pragma unroll 1
    for (int q = 0; q < 4; ++q) {
        const int c4 = cbase + q * 4;
        float res0[4] = {0,0,0,0}, res1[4] = {0,0,0,0};
        float xm0[4], xm1[4];
        #pragma unroll
        for (int ci = 0; ci < 6; ++ci) {
            const int cc  = c4 - 1 + ci;
            const bool cok = (cc >= 0) && (cc < C_);
            const int ccl = cc < 0 ? 0 : (cc > C_ - 1 ? C_ - 1 : cc);
            const float* pc = xb + (size_t)ccl * HW_ + lw;
            #pragma unroll
            for (int jr = 0; jr < 4; ++jr) {
                float v;
                bool keep = cok && (lane < W_);
                if (EDGE) {
                    const int hh  = h0 - 1 + jr;
                    keep = keep && (hh >= 0) && (hh < H_);
                    const int hcl = hh < 0 ? 0 : (hh > H_ - 1 ? H_ - 1 : hh);
                    v = pc[hcl * W_];
                } else {
                    v = pc[(h0 - 1 + jr) * W_];
                }
                v = keep ? v : 0.f;
                // residual capture: center channel (cc==c4+ci-1), rows h0/h0+1
                if (ci >= 1 && ci <= 4) {
                    if (jr == 1) xm0[ci - 1] = v;
                    if (jr == 2) xm1[ci - 1] = v;
                }
                const float vl = dpp_shr1(v);           // lane0 -> 0 (bound_ctrl)
                const float vr = dpp_shl1(v);           // lane55 -> v[56]==0
                #pragma unroll
                for (int kl = 0; kl < 4; ++kl) {
                    const int dz = ci - kl;             // weight channel offset
                    if (dz >= 0 && dz <= 2) {
                        if (jr <= 2) {                  // output row h0, dy=jr
                            const int wi = (dz * 3 + jr) * 3;
                            res0[kl] = fmaf(W3[wi], vl, fmaf(W3[wi+1], v, fmaf(W3[wi+2], vr, res0[kl])));
                        }
                        if (jr >= 1) {                  // output row h0+1, dy=jr-1
                            const int wi = (dz * 3 + jr - 1) * 3;
                            res1[kl] = fmaf(W3[wi], vl, fmaf(W3[wi+1], v, fmaf(W3[wi+2], vr, res1[kl])));
                        }
                    }
                }
            }
        }
        if (lane < W_) {
            const ush4 q0 = *(const ush4*)&sg0[lane * SGPT + c4];   // 4 gates, one b64
            const ush4 q1 = *(const ush4*)&sg1[lane * SGPT + c4];
            #pragma unroll
            for (int kk = 0; kk < 4; ++kk) {
                const int c = c4 + kk;
                const size_t xi = ((size_t)c * H_ + h0) * W_ + lane;
                outb[xi]      = fmaf(res0[kk], bf2f(q0[kk]) * invS0, xm0[kk]);
                outb[xi + W_] = fmaf(res1[kk], bf2f(q1[kk]) * invS1, xm1[kk]);
            }
        }
    }
}

// ---------- K3: fused CP-reconstruct + softmax + conv3d gate ----------
// Staging remapped (1 c per thread -> 3 gapc loads, not 48). MFMA rows FUSED:
// one set of scout/swout fragment reads feeds both h-rows (acc[8]).
__global__ __launch_bounds__(1024)
void k_main(
    const float* __restrict__ x,
    const float* __restrict__ Wc, const float* __restrict__ acp,
    const float* __restrict__ Ww, const float* __restrict__ awp,
    const float* __restrict__ Wh, const float* __restrict__ ahp,
    const float* __restrict__ W3,
    const float* __restrict__ gapc, const float* __restrict__ gw,
    const float* __restrict__ gh,
    float* __restrict__ out)
{
    __shared__ __align__(16) char smem[SMEM_SZ];
    unsigned short* sg0   = (unsigned short*)(smem + OFF_SG0T);
    unsigned short* scout = (unsigned short*)(smem + OFF_SCOUT);
    unsigned short* sg1   = scout;                          // alias, post-bar2
    unsigned short* swout = (unsigned short*)(smem + OFF_SWOUT);
    float* sred0 = (float*)(smem + OFF_SRED0);              // alias swout
    float* sred1 = (float*)(smem + OFF_SRED1);
    float* shout = (float*)(smem + OFF_SHOUT);

    // swizzled decode: blocks round-robin XCDs; each XCD owns 4 whole batches
    const int bid  = blockIdx.x;
    const int slot = bid >> 3;
    const int b    = (bid & 7) * 4 + slot / NHT;
    const int h0   = (slot % NHT) * 2;

    const int tid  = threadIdx.x;
    const int lane = tid & 63;
    const int wid  = tid >> 6;
    const int g    = lane >> 4;
    const int col  = lane & 15;
    const int lw   = (lane < W_) ? lane : (W_ - 1);
    const float ac = acp[0], aw = awp[0], ah = ahp[0];

    // ----- staging: one c (or w) per thread; factor rows from GAP results -----
    {   // scout: c = tid>>2 (0..255), r = (tid&3)*16 .. +15
        const float* gc = gapc + b * C_;
        const int c  = tid >> 2;
        const int rq = tid & 3;
        const float gm = (c >= 1)      ? gc[c - 1] : 0.f;
        const float g0 = gc[c];
        const float gp = (c < C_ - 1)  ? gc[c + 1] : 0.f;
        const float* wc = Wc + rq * 48;
        unsigned short* dst = &scout[c * CPH + rq * 16];
        #pragma unroll
        for (int i = 0; i < 16; i += 4) {
            f32x4 vv;
            #pragma unroll
            for (int k = 0; k < 4; ++k) {
                float v = wc[(i+k)*3+0] * gm + wc[(i+k)*3+1] * g0 + wc[(i+k)*3+2] * gp;
                vv[k] = (v >= 0.f) ? v : ac * v;
            }
            u32x2 pkd = { pkbf(vv[0], vv[1]), pkbf(vv[2], vv[3]) };
            *(u32x2*)&dst[i] = pkd;
        }
    }
    {   // swout: w = tid>>4 (0..63), r = (tid&15)*4 .. +3
        const float* gwb = gw + b * W_;
        const int w  = tid >> 4;
        const int rq = tid & 15;
        float gm = 0.f, g0 = 0.f, gp = 0.f;
        if (w < W_) {
            gm = (w >= 1)     ? gwb[w - 1] * (1.f / CH_) : 0.f;
            g0 = gwb[w] * (1.f / CH_);
            gp = (w < W_ - 1) ? gwb[w + 1] * (1.f / CH_) : 0.f;
        }
        const float* ww = Ww + rq * 12;
        f32x4 vv;
        #pragma unroll
        for (int k = 0; k < 4; ++k) {
            float v = ww[k*3+0] * gm + ww[k*3+1] * g0 + ww[k*3+2] * gp;
            vv[k] = (v >= 0.f) ? v : aw * v;
        }
        u32x2 pkd = { pkbf(vv[0], vv[1]), pkbf(vv[2], vv[3]) };
        *(u32x2*)&swout[w * CPH + rq * 4] = pkd;
    }
    if (tid < 2 * 64) {   // shout (f32)
        const float* ghb = gh + b * H_;
        const int hr = tid >> 6, r = tid & 63;
        const int h = h0 + hr;
        const float gm = (h >= 1)     ? ghb[h - 1] * (1.f / CH_) : 0.f;
        const float g0 = ghb[h] * (1.f / CH_);
        const float gp = (h < H_ - 1) ? ghb[h + 1] * (1.f / CH_) : 0.f;
        float v = Wh[r * 3 + 0] * gm + Wh[r * 3 + 1] * g0 + Wh[r * 3 + 2] * gp;
        shout[hr * CPH + r] = (v >= 0.f) ? v : ah * v;
    }
    __syncthreads();                                        // bar1

    const int cbase = wid * 16;
    const int crow  = cbase + col;
    const int cr    = cbase + g * 4;

    // ----- MFMA both rows fused: one fragment read feeds 2 MFMAs -----
    f32x4 acc[8];                   // 0-3: row0 tiles t=0..3; 4-7: row1
    #pragma unroll
    for (int t = 0; t < 8; ++t) acc[t] = (f32x4){0,0,0,0};
    #pragma unroll
    for (int kc = 0; kc < 2; ++kc) {
        const int r0 = kc * 32 + g * 4;
        f32x4 ca = bf2f4(*(ush4*)&scout[crow * CPH + r0]);
        f32x4 cb = bf2f4(*(ush4*)&scout[crow * CPH + r0 + 16]);
        f32x4 ha0 = *(f32x4*)&shout[0 * CPH + r0];
        f32x4 hb0 = *(f32x4*)&shout[0 * CPH + r0 + 16];
        f32x4 ha1 = *(f32x4*)&shout[1 * CPH + r0];
        f32x4 hb1 = *(f32x4*)&shout[1 * CPH + r0 + 16];
        s16x8 af0 = pack8(ca * ha0, cb * hb0);
        s16x8 af1 = pack8(ca * ha1, cb * hb1);
        #pragma unroll
        for (int t = 0; t < 4; ++t) {
            s16x8 bfr = cat8(*(ush4*)&swout[(t*16+col)*CPH + r0],
                             *(ush4*)&swout[(t*16+col)*CPH + r0 + 16]);
            acc[t]     = __builtin_amdgcn_mfma_f32_16x16x32_bf16(af0, bfr, acc[t],     0, 0, 0);
            acc[4 + t] = __builtin_amdgcn_mfma_f32_16x16x32_bf16(af1, bfr, acc[4 + t], 0, 0, 0);
        }
    }
    // exp + wave-partial sums (f32 butterfly); write row0 e-tile to sg0
    float s0p, s1p;
    {
        float st0[4], st1[4];
        #pragma unroll
        for (int t = 0; t < 4; ++t) {
            #pragma unroll
            for (int j = 0; j < 4; ++j) { acc[t][j] = __expf(acc[t][j]); acc[4+t][j] = __expf(acc[4+t][j]); }
            float s0 = acc[t][0] + acc[t][1] + acc[t][2] + acc[t][3];
            float s1 = acc[4+t][0] + acc[4+t][1] + acc[4+t][2] + acc[4+t][3];
            s0 += __shfl_xor(s0, 16, 64);  s0 += __shfl_xor(s0, 32, 64);
            s1 += __shfl_xor(s1, 16, 64);  s1 += __shfl_xor(s1, 32, 64);
            st0[t] = s0; st1[t] = s1;
        }
        s0p = (g == 0) ? st0[0] : (g == 1) ? st0[1] : (g == 2) ? st0[2] : st0[3];
        s1p = (g == 0) ? st1[0] : (g == 1) ? st1[1] : (g == 2) ? st1[2] : st1[3];
        #pragma unroll
        for (int t = 0; t < 4; ++t) {
            const int w = t * 16 + col;
            if (w < W_) {
                u32x2 pkd = { pkbf(acc[t][0], acc[t][1]), pkbf(acc[t][2], acc[t][3]) };
                *(u32x2*)&sg0[w * SGPT + cr] = pkd;
            }
        }
    }
    __syncthreads();                                        // bar2: scout/swout reads done
    {
        #pragma unroll
        for (int t = 0; t < 4; ++t) {
            const int w = t * 16 + col;
            if (w < W_) {
                u32x2 pkd = { pkbf(acc[4+t][0], acc[4+t][1]), pkbf(acc[4+t][2], acc[4+t][3]) };
                *(u32x2*)&sg1[w * SGPT + cr] = pkd;
            }
        }
        sred0[wid * 64 + lane] = s0p;
        sred1[wid * 64 + lane] = s1p;
    }
    __syncthreads();                                        // bar3

    float invS0, invS1;
    {
        float T0 = 0.f, T1 = 0.f;
        #pragma unroll
        for (int t = 0; t < 16; ++t) {
            T0 += sred0[t * 64 + lane];
            T1 += sred1[t * 64 + lane];
        }
        invS0 = 1.f / T0;
        invS1 = 1.f / T1;
    }

    const float* xb = x + (size_t)b * C_ * HW_;
    float* outb = out + (size_t)b * C_ * HW_;
    if (h0 == 0 || h0 == H_ - 2)
        conv_store<true >(xb, W3, sg0, sg1, invS0, invS1, h0, cbase, lane, lw, outb);
    else
        conv_store<false>(xb, W3, sg0, sg1, invS0, invS1, h0, cbase, lane, lw, outb);
}

extern "C" void kernel_launch(void* const* d_in, const int* in_sizes, int n_in,
                              void* d_out, int out_size, void* d_ws, size_t ws_size,
                              hipStream_t stream) {
    const float* x  = (const float*)d_in[0];
    const float* Wc = (const float*)d_in[1];
    const float* ac = (const float*)d_in[2];
    const float* Ww = (const float*)d_in[3];
    const float* aw = (const float*)d_in[4];
    const float* Wh = (const float*)d_in[5];
    const float* ah = (const float*)d_in[6];
    const float* W3 = (const float*)d_in[7];
    float* out  = (float*)d_out;
    float* gapc = (float*)d_ws;                 // B*C
    float* gwp  = gapc + B_ * C_;               // B*W (raw sums)
    float* ghp  = gwp + B_ * W_;                // B*H (raw sums)

    (void)hipMemsetAsync(gwp, 0, (size_t)(B_ * W_ + B_ * H_) * sizeof(float), stream);
    k_reduce<<<dim3(B_ * (C_ / CGRP)), dim3(832), 0, stream>>>(x, gapc, gwp, ghp);
    k_main<<<dim3(B_ * NHT), dim3(1024), 0, stream>>>(
        x, Wc, ac, Ww, aw, Wh, ah, W3, gapc, gwp, ghp, out);
}